// Round 1
// baseline (2605.697 us; speedup 1.0000x reference)
//
#include <hip/hip_runtime.h>

#define NHEADS 12

constexpr float SCALE = 0.125f;   // 64^-0.5
constexpr float EPS_RMS = 1e-6f;

// ============ G1: QKV of the 4 global tokens (4 x 2304) ============
__global__ void k_gqkv(const float* __restrict__ gtok,
                       const float* __restrict__ w_qkv,
                       float* __restrict__ qkv_g) {
  int idx = blockIdx.x * 256 + threadIdx.x;   // 0..9215
  int tok = idx / 2304, c = idx - tok * 2304;
  const float* gp = gtok + tok * 768;
  float s = 0.f;
  for (int d = 0; d < 768; ++d) s += gp[d] * w_qkv[d * 2304 + c];
  qkv_g[idx] = s;
}

// ============ L: fused QKV + rmsnorm + local window attention ============
// grid = 512 windows, block = 256. Writes o_local into `out` (d_out as scratch)
// and per-(window,head) global-attention partials into `part`.
__global__ __launch_bounds__(256, 2) void k_local(
    const float* __restrict__ x,
    const float* __restrict__ w_qkv,
    const float* __restrict__ qnw,
    const float* __restrict__ knw,
    const float* __restrict__ qkv_g,
    float* __restrict__ part,
    float* __restrict__ out) {
  __shared__ __align__(16) float q_s[64 * 68];
  __shared__ __align__(16) float k_s[64 * 68];
  __shared__ __align__(16) float v_s[64 * 68];
  __shared__ __align__(16) float stage[4224];   // xs[64][17] + wcs[16][196] | sps[64][66]
  __shared__ float ps_c[256];

  const int tid = threadIdx.x;
  const int wi = blockIdx.x;
  const int b = wi >> 6;
  const int widx = wi & 63;
  const int wr = widx >> 3, wcl = widx & 7;
  const int base_t = (b << 12) + ((wr * 8) << 6) + wcl * 8;

  const int ty = tid >> 4;   // 16 row groups x 4 rows
  const int tx = tid & 15;   // 16 col groups x 12 cols

  float* xs  = stage;            // [64][17]
  float* wcs = stage + 64 * 17;  // [16][196]
  float* sps = stage;            // [64][66] alias for phase B

  // precomputed load offsets (head/chunk independent parts)
  int x_g[4], x_l[4];
#pragma unroll
  for (int e = 0; e < 4; ++e) {
    int idx = e * 256 + tid;
    int l = idx >> 4, kk = idx & 15;
    int row = base_t + ((l >> 3) << 6) + (l & 7);
    x_g[e] = row * 768 + kk;
    x_l[e] = l * 17 + kk;
  }
  int w_g[12], w_l[12];
#pragma unroll
  for (int e = 0; e < 12; ++e) {
    int idx = e * 256 + tid;
    int r = idx / 192, c = idx - r * 192;
    w_g[e] = r * 2304 + (c >> 6) * 768 + (c & 63);
    w_l[e] = r * 196 + c;
  }

  for (int h = 0; h < NHEADS; ++h) {
    const int hw = h * 64;
    // ======== Phase A: qkv_h(64x192) = x_win(64x768) @ W_h(768x192) ========
    float acc[4][12];
#pragma unroll
    for (int i = 0; i < 4; ++i)
#pragma unroll
      for (int j = 0; j < 12; ++j) acc[i][j] = 0.f;

    float xr[4], wrg[12];
#pragma unroll
    for (int e = 0; e < 4; ++e) xr[e] = x[x_g[e]];
#pragma unroll
    for (int e = 0; e < 12; ++e) wrg[e] = w_qkv[w_g[e] + hw];

    for (int ch = 0; ch < 48; ++ch) {
#pragma unroll
      for (int e = 0; e < 4; ++e) xs[x_l[e]] = xr[e];
#pragma unroll
      for (int e = 0; e < 12; ++e) wcs[w_l[e]] = wrg[e];
      __syncthreads();
      if (ch + 1 < 48) {                 // register-prefetch next K-chunk
        int k0 = (ch + 1) * 16;
#pragma unroll
        for (int e = 0; e < 4; ++e) xr[e] = x[x_g[e] + k0];
#pragma unroll
        for (int e = 0; e < 12; ++e) wrg[e] = w_qkv[w_g[e] + k0 * 2304 + hw];
      }
#pragma unroll
      for (int kk = 0; kk < 16; ++kk) {
        float a[4], bb[12];
#pragma unroll
        for (int i = 0; i < 4; ++i) a[i] = xs[(ty * 4 + i) * 17 + kk];
#pragma unroll
        for (int j = 0; j < 12; ++j) bb[j] = wcs[kk * 196 + tx * 12 + j];
#pragma unroll
        for (int i = 0; i < 4; ++i)
#pragma unroll
          for (int j = 0; j < 12; ++j) acc[i][j] += a[i] * bb[j];
      }
      __syncthreads();
    }
    // scatter qkv_h to LDS
#pragma unroll
    for (int i = 0; i < 4; ++i) {
      int row = ty * 4 + i;
#pragma unroll
      for (int j = 0; j < 12; ++j) {
        int c = tx * 12 + j;
        float* dst = (c < 64) ? q_s : (c < 128) ? k_s : v_s;
        dst[row * 68 + (c & 63)] = acc[i][j];
      }
    }
    __syncthreads();

    // ======== Phase C: global-attn partials over this window (raw k,v) ========
    {
      int qi = tid >> 6, j = tid & 63;     // wave == query qi
      const float* qgp = qkv_g + qi * 2304 + hw;
      float s = 0.f;
      for (int d = 0; d < 64; ++d) s += qgp[d] * k_s[j * 68 + d];
      s *= SCALE;
      float m = s;
#pragma unroll
      for (int o = 1; o < 64; o <<= 1) m = fmaxf(m, __shfl_xor(m, o));
      float p = expf(s - m);
      float l = p;
#pragma unroll
      for (int o = 1; o < 64; o <<= 1) l += __shfl_xor(l, o);
      ps_c[qi * 64 + j] = p;
      int pbase = ((b * 12 + h) * 64 + widx) * 272;
      if (j == 0) { part[pbase + 256 + qi] = m; part[pbase + 260 + qi] = l; }
      __syncthreads();
      float a = 0.f;
      for (int jj = 0; jj < 64; ++jj) a += ps_c[qi * 64 + jj] * v_s[jj * 68 + j];
      part[pbase + qi * 64 + j] = a;
    }

    // ======== Phase A2: rmsnorm(q), rmsnorm(k) in LDS ========
    if (tid < 128) {
      int which = tid >> 6, tok = tid & 63;
      float* row = which ? (k_s + tok * 68) : (q_s + tok * 68);
      const float* nw = which ? knw : qnw;
      float ss = 0.f;
      for (int d = 0; d < 64; ++d) { float v0 = row[d]; ss += v0 * v0; }
      float sc = 1.0f / sqrtf(ss * 0.015625f + EPS_RMS);
      for (int d = 0; d < 64; ++d) row[d] = row[d] * sc * nw[d];
    }
    __syncthreads();

    // ======== Phase B: local attention for this head ========
    {
      int i = tid >> 2, g = tid & 3;       // row i, 16-col slab g
      float sv[16];
#pragma unroll
      for (int jj = 0; jj < 16; ++jj) sv[jj] = 0.f;
      for (int d = 0; d < 64; ++d) {
        float qa = q_s[i * 68 + d];
#pragma unroll
        for (int jj = 0; jj < 16; ++jj) sv[jj] += qa * k_s[(g * 16 + jj) * 68 + d];
      }
      float m = -1e30f;
#pragma unroll
      for (int jj = 0; jj < 16; ++jj) { sv[jj] *= SCALE; m = fmaxf(m, sv[jj]); }
      m = fmaxf(m, __shfl_xor(m, 1));
      m = fmaxf(m, __shfl_xor(m, 2));
      float l = 0.f;
#pragma unroll
      for (int jj = 0; jj < 16; ++jj) { sv[jj] = expf(sv[jj] - m); l += sv[jj]; }
      l += __shfl_xor(l, 1);
      l += __shfl_xor(l, 2);
#pragma unroll
      for (int jj = 0; jj < 16; ++jj) sps[i * 66 + g * 16 + jj] = sv[jj];
      __syncthreads();
      float oa[16];
#pragma unroll
      for (int dd = 0; dd < 16; ++dd) oa[dd] = 0.f;
      for (int j = 0; j < 64; ++j) {
        float pv = sps[i * 66 + j];
#pragma unroll
        for (int dd = 0; dd < 16; ++dd) oa[dd] += pv * v_s[j * 68 + g * 16 + dd];
      }
      float invl = 1.0f / l;
      int orow = (base_t + ((i >> 3) << 6) + (i & 7)) * 768 + hw + g * 16;
#pragma unroll
      for (int dd = 0; dd < 16; ++dd) out[orow + dd] = oa[dd] * invl;
    }
    __syncthreads();
  }
}

// ============ G3: combine global-attn partials -> og_mean (B x 768) ============
__global__ void k_greduce(const float* __restrict__ qkv_g,
                          const float* __restrict__ part,
                          float* __restrict__ og_mean) {
  __shared__ float red[4][64];
  int bh = blockIdx.x;
  int b = bh / 12, h = bh - b * 12;
  int tid = threadIdx.x;
  int qi = tid >> 6, d = tid & 63;
  float M = -1e30f, L = 0.f, A = 0.f;
  float qd = qkv_g[qi * 2304 + h * 64 + d];
  // 4 global-token keys
#pragma unroll
  for (int gk = 0; gk < 4; ++gk) {
    float kd = qkv_g[gk * 2304 + 768 + h * 64 + d];
    float prod = qd * kd;
#pragma unroll
    for (int o = 1; o < 64; o <<= 1) prod += __shfl_xor(prod, o);
    float s = prod * SCALE;
    float Mn = fmaxf(M, s);
    float f = expf(M - Mn), e = expf(s - Mn);
    float vd = qkv_g[gk * 2304 + 1536 + h * 64 + d];
    A = A * f + e * vd;
    L = L * f + e;
    M = Mn;
  }
  // 64 window partials
  for (int p = 0; p < 64; ++p) {
    int pbase = ((b * 12 + h) * 64 + p) * 272;
    float mp = part[pbase + 256 + qi];
    float lp = part[pbase + 260 + qi];
    float ap = part[pbase + qi * 64 + d];
    float Mn = fmaxf(M, mp);
    float f = expf(M - Mn), e = expf(mp - Mn);
    A = A * f + ap * e;
    L = L * f + lp * e;
    M = Mn;
  }
  red[qi][d] = A / L;
  __syncthreads();
  if (tid < 64) {
    float s = (red[0][d] + red[1][d] + red[2][d] + red[3][d]) * 0.25f;
    og_mean[b * 768 + h * 64 + d] = s;
  }
}

// ============ G4: g_term = og_mean @ w_out (B x 768) ============
__global__ void k_gterm(const float* __restrict__ og_mean,
                        const float* __restrict__ w_out,
                        float* __restrict__ g_term) {
  int idx = blockIdx.x * 256 + threadIdx.x;   // 0..6143
  int b = idx / 768, c = idx - b * 768;
  const float* op = og_mean + b * 768;
  float s = 0.f;
  for (int d = 0; d < 768; ++d) s += op[d] * w_out[d * 768 + c];
  g_term[idx] = s;
}

// ============ P: in-place projection out = o_local @ w_out + g_term ============
// grid = 2048 (16 rows each), block = 256
__global__ __launch_bounds__(256, 2) void k_proj(
    const float* __restrict__ w_out,
    const float* __restrict__ g_term,
    float* __restrict__ io) {
  __shared__ __align__(16) float As[16 * 772];
  __shared__ __align__(16) float Ws[8 * 772];
  const int tid = threadIdx.x;
  const int r0 = blockIdx.x * 16;
  const int b = r0 >> 12;
  // load full 16x768 A tile (own rows) before any write: in-place safe
#pragma unroll
  for (int e = 0; e < 48; ++e) {
    int idx = e * 256 + tid;
    int r = idx / 768;
    As[idx + 4 * r] = io[r0 * 768 + idx];
  }
  int wl[24];
#pragma unroll
  for (int e = 0; e < 24; ++e) {
    int idx = e * 256 + tid;
    wl[e] = idx + 4 * (idx / 768);
  }
  float wreg[24];
#pragma unroll
  for (int e = 0; e < 24; ++e) wreg[e] = w_out[e * 256 + tid];
  float acc[4][12];
#pragma unroll
  for (int i = 0; i < 4; ++i)
#pragma unroll
    for (int j = 0; j < 12; ++j) acc[i][j] = 0.f;
  const int ty = tid >> 6;
  const int tx = tid & 63;
  __syncthreads();
  for (int ch = 0; ch < 96; ++ch) {
#pragma unroll
    for (int e = 0; e < 24; ++e) Ws[wl[e]] = wreg[e];
    __syncthreads();
    if (ch + 1 < 96) {                    // register-prefetch next W chunk
      int gb = (ch + 1) * 8 * 768;
#pragma unroll
      for (int e = 0; e < 24; ++e) wreg[e] = w_out[gb + e * 256 + tid];
    }
    const int kb = ch * 8;
#pragma unroll
    for (int kk = 0; kk < 8; ++kk) {
      float a[4], bb[12];
#pragma unroll
      for (int i = 0; i < 4; ++i) a[i] = As[(ty * 4 + i) * 772 + kb + kk];
#pragma unroll
      for (int j = 0; j < 12; ++j) bb[j] = Ws[kk * 772 + tx * 12 + j];
#pragma unroll
      for (int i = 0; i < 4; ++i)
#pragma unroll
        for (int j = 0; j < 12; ++j) acc[i][j] += a[i] * bb[j];
    }
    __syncthreads();
  }
#pragma unroll
  for (int i = 0; i < 4; ++i) {
    int row = (r0 + ty * 4 + i) * 768;
#pragma unroll
    for (int j = 0; j < 12; ++j) {
      int c = tx * 12 + j;
      io[row + c] = acc[i][j] + g_term[b * 768 + c];
    }
  }
}

extern "C" void kernel_launch(void* const* d_in, const int* in_sizes, int n_in,
                              void* d_out, int out_size, void* d_ws, size_t ws_size,
                              hipStream_t stream) {
  const float* x      = (const float*)d_in[0];
  const float* w_qkv  = (const float*)d_in[1];
  const float* w_out  = (const float*)d_in[2];
  const float* qnw    = (const float*)d_in[3];
  const float* knw    = (const float*)d_in[4];
  const float* gtok   = (const float*)d_in[5];
  float* out = (float*)d_out;
  float* ws = (float*)d_ws;

  float* qkv_g   = ws;                       // 4*2304            = 9216
  float* part    = qkv_g + 9216;             // 8*12*64*272       = 1671168
  float* og_mean = part + 8 * 12 * 64 * 272; // 8*768             = 6144
  float* g_term  = og_mean + 6144;           // 8*768             = 6144
  // total ~6.77 MB of d_ws

  k_gqkv   <<<36,   256, 0, stream>>>(gtok, w_qkv, qkv_g);
  k_local  <<<512,  256, 0, stream>>>(x, w_qkv, qnw, knw, qkv_g, part, out);
  k_greduce<<<96,   256, 0, stream>>>(qkv_g, part, og_mean);
  k_gterm  <<<24,   256, 0, stream>>>(og_mean, w_out, g_term);
  k_proj   <<<2048, 256, 0, stream>>>(w_out, g_term, out);
}

// Round 2
// 1833.878 us; speedup vs baseline: 1.4209x; 1.4209x over previous
//
#include <hip/hip_runtime.h>
#include <hip/hip_bf16.h>

typedef short short8 __attribute__((ext_vector_type(8)));
typedef float f32x4 __attribute__((ext_vector_type(4)));

constexpr float SCALE = 0.125f;   // 64^-0.5
constexpr float EPS_RMS = 1e-6f;

__device__ __forceinline__ unsigned short f2bf(float f) {
  return __builtin_bit_cast(unsigned short, __float2bfloat16(f));
}
__device__ __forceinline__ float bf2f(unsigned short u) {
  return __bfloat162float(__builtin_bit_cast(__hip_bfloat16, u));
}
__device__ __forceinline__ unsigned int pack_hl(float f) {
  unsigned short h = f2bf(f);
  unsigned short l = f2bf(f - bf2f(h));
  return ((unsigned int)h << 16) | (unsigned int)l;
}

// ============ P0: transpose + split weights into bf16 hi/lo planes ============
// mode 0: w_qkv (768 x 2304), output rows permuted to [head][q|k|v][64] order.
// mode 1: w_out (768 x 768), identity column map.
// Output: hi/lo [n_rows][768] bf16, row r = output column, inner = k.
__global__ void k_prep(const float* __restrict__ src, int src_ld, int mode,
                       unsigned short* __restrict__ hi, unsigned short* __restrict__ lo) {
  __shared__ float tile[64][65];
  int rb = blockIdx.x, db = blockIdx.y;
  int tid = threadIdx.x;
#pragma unroll
  for (int e = 0; e < 16; ++e) {
    int idx = e * 256 + tid;
    int dd = idx >> 6, cc = idx & 63;
    int sc;
    if (mode == 0) { int h = rb / 3, p = rb % 3; sc = p * 768 + h * 64 + cc; }
    else sc = rb * 64 + cc;
    tile[dd][cc] = src[(db * 64 + dd) * src_ld + sc];
  }
  __syncthreads();
#pragma unroll
  for (int e = 0; e < 16; ++e) {
    int idx = e * 256 + tid;
    int cc = idx >> 6, dd = idx & 63;
    float f = tile[dd][cc];
    unsigned short h = f2bf(f);
    unsigned short l = f2bf(f - bf2f(h));
    int o = (rb * 64 + cc) * 768 + db * 64 + dd;
    hi[o] = h;
    lo[o] = l;
  }
}

// ============ G1: QKV of the 4 global tokens (4 x 2304), fp32 ============
__global__ void k_gqkv(const float* __restrict__ gtok,
                       const float* __restrict__ w_qkv,
                       float* __restrict__ qkv_g) {
  int idx = blockIdx.x * 256 + threadIdx.x;   // 0..9215
  int tok = idx / 2304, c = idx - tok * 2304;
  const float* gp = gtok + tok * 768;
  float s = 0.f;
  for (int d = 0; d < 768; ++d) s += gp[d] * w_qkv[d * 2304 + c];
  qkv_g[idx] = s;
}

// ============ L: fused MFMA-QKV + rmsnorm + local window attention ============
// grid = 512 windows, block = 256 (4 waves). o written packed hi/lo to opack.
__global__ __launch_bounds__(256, 2) void k_local(
    const float* __restrict__ x,
    const unsigned short* __restrict__ Whi,
    const unsigned short* __restrict__ Wlo,
    const float* __restrict__ qnw,
    const float* __restrict__ knw,
    const float* __restrict__ qkv_g,
    float* __restrict__ part,
    unsigned int* __restrict__ opack) {
  __shared__ __align__(16) float qs[64 * 68];
  __shared__ __align__(16) float ks[64 * 68];
  __shared__ __align__(16) float vs[64 * 68];
  __shared__ __align__(16) unsigned short Bst[2][192 * 32];  // swizzled W chunk

  float* sps  = (float*)&Bst[0][0];      // [64][66] alias, phase B
  float* ps_c = sps + 64 * 66;           // [256] alias, phase C

  const int tid = threadIdx.x;
  const int lane = tid & 63;
  const int wv = tid >> 6;
  const int wi = blockIdx.x;
  const int b = wi >> 6;
  const int widx = wi & 63;
  const int wr = widx >> 3, wcl = widx & 7;
  const int base_t = (b << 12) + (wr << 9) + wcl * 8;

  // A-fragment source: token row for this lane (A row = lane&15)
  const int tok = wv * 16 + (lane & 15);
  const int grow = base_t + ((tok >> 3) << 6) + (tok & 7);
  const int kb = lane >> 4;                         // k-block 0..3
  const float* aptr = x + grow * 768 + kb * 8;

  for (int h = 0; h < 12; ++h) {
    const int hb = h * 192;
    f32x4 acc[12];
#pragma unroll
    for (int t = 0; t < 12; ++t) acc[t] = (f32x4){0.f, 0.f, 0.f, 0.f};

    // prologue: B chunk 0 regs + A chunk 0 regs
    uint4 breg[6];
#pragma unroll
    for (int e = 0; e < 3; ++e) {
      int idx = e * 256 + tid;
      int c = idx >> 2, u = idx & 3;
      breg[e]     = *(const uint4*)(Whi + (hb + c) * 768 + u * 8);
      breg[e + 3] = *(const uint4*)(Wlo + (hb + c) * 768 + u * 8);
    }
    float4 a0 = *(const float4*)(aptr);
    float4 a1 = *(const float4*)(aptr + 4);

    for (int kc = 0; kc < 24; ++kc) {
      // write staged B to LDS (XOR-swizzled 16B units)
#pragma unroll
      for (int e = 0; e < 3; ++e) {
        int idx = e * 256 + tid;
        int c = idx >> 2, u = idx & 3;
        int pu = u ^ ((c >> 1) & 3);
        *(uint4*)&Bst[0][c * 32 + pu * 8] = breg[e];
        *(uint4*)&Bst[1][c * 32 + pu * 8] = breg[e + 3];
      }
      __syncthreads();
      if (kc + 1 < 24) {  // prefetch next B chunk
#pragma unroll
        for (int e = 0; e < 3; ++e) {
          int idx = e * 256 + tid;
          int c = idx >> 2, u = idx & 3;
          breg[e]     = *(const uint4*)(Whi + (hb + c) * 768 + (kc + 1) * 32 + u * 8);
          breg[e + 3] = *(const uint4*)(Wlo + (hb + c) * 768 + (kc + 1) * 32 + u * 8);
        }
      }
      // split A chunk to bf16 hi/lo fragments
      float av0 = a0.x, av1 = a0.y, av2 = a0.z, av3 = a0.w;
      float av4 = a1.x, av5 = a1.y, av6 = a1.z, av7 = a1.w;
      short8 ah, al;
      {
        float av[8] = {av0, av1, av2, av3, av4, av5, av6, av7};
#pragma unroll
        for (int j = 0; j < 8; ++j) {
          unsigned short hb_ = f2bf(av[j]);
          ah[j] = (short)hb_;
          al[j] = (short)f2bf(av[j] - bf2f(hb_));
        }
      }
      if (kc + 1 < 24) {  // prefetch next A chunk
        a0 = *(const float4*)(aptr + (kc + 1) * 32);
        a1 = *(const float4*)(aptr + (kc + 1) * 32 + 4);
      }
      // 12 col-tiles x 4 split products
#pragma unroll
      for (int t = 0; t < 12; ++t) {
        int c = t * 16 + (lane & 15);
        int pu = kb ^ ((c >> 1) & 3);
        short8 bh = *(const short8*)&Bst[0][c * 32 + pu * 8];
        short8 bl = *(const short8*)&Bst[1][c * 32 + pu * 8];
        acc[t] = __builtin_amdgcn_mfma_f32_16x16x32_bf16(ah, bh, acc[t], 0, 0, 0);
        acc[t] = __builtin_amdgcn_mfma_f32_16x16x32_bf16(ah, bl, acc[t], 0, 0, 0);
        acc[t] = __builtin_amdgcn_mfma_f32_16x16x32_bf16(al, bh, acc[t], 0, 0, 0);
        acc[t] = __builtin_amdgcn_mfma_f32_16x16x32_bf16(al, bl, acc[t], 0, 0, 0);
      }
      __syncthreads();
    }

    // scatter accumulators -> q/k/v LDS (C layout: col=lane&15, row=(lane>>4)*4+r)
#pragma unroll
    for (int t = 0; t < 12; ++t) {
      float* dst = (t < 4) ? qs : (t < 8) ? ks : vs;
      int cc = (t & 3) * 16 + (lane & 15);
      int rbase = wv * 16 + (lane >> 4) * 4;
#pragma unroll
      for (int r = 0; r < 4; ++r) dst[(rbase + r) * 68 + cc] = acc[t][r];
    }
    __syncthreads();

    // ======== Phase C: global-attn partials over this window (raw k,v) ========
    {
      int qi = tid >> 6, j = tid & 63;
      const float* qgp = qkv_g + qi * 2304 + h * 64;
      float s = 0.f;
      for (int d = 0; d < 64; ++d) s += qgp[d] * ks[j * 68 + d];
      s *= SCALE;
      float m = s;
#pragma unroll
      for (int o = 1; o < 64; o <<= 1) m = fmaxf(m, __shfl_xor(m, o));
      float p = expf(s - m);
      float l = p;
#pragma unroll
      for (int o = 1; o < 64; o <<= 1) l += __shfl_xor(l, o);
      ps_c[qi * 64 + j] = p;
      int pbase = ((b * 12 + h) * 64 + widx) * 272;
      if (j == 0) { part[pbase + 256 + qi] = m; part[pbase + 260 + qi] = l; }
      __syncthreads();
      float a = 0.f;
      for (int jj = 0; jj < 64; ++jj) a += ps_c[qi * 64 + jj] * vs[jj * 68 + j];
      part[pbase + qi * 64 + j] = a;
    }

    // ======== rmsnorm(q), rmsnorm(k) in LDS ========
    if (tid < 128) {
      int which = tid >> 6, tk = tid & 63;
      float* row = which ? (ks + tk * 68) : (qs + tk * 68);
      const float* nw = which ? knw : qnw;
      float ss = 0.f;
      for (int d = 0; d < 64; ++d) { float v0 = row[d]; ss += v0 * v0; }
      float sc = 1.0f / sqrtf(ss * 0.015625f + EPS_RMS);
      for (int d = 0; d < 64; ++d) row[d] = row[d] * sc * nw[d];
    }
    __syncthreads();

    // ======== Phase B: local attention for this head ========
    {
      int i = tid >> 2, g = tid & 3;
      float sv[16];
#pragma unroll
      for (int jj = 0; jj < 16; ++jj) sv[jj] = 0.f;
      for (int d = 0; d < 64; ++d) {
        float qa = qs[i * 68 + d];
#pragma unroll
        for (int jj = 0; jj < 16; ++jj) sv[jj] += qa * ks[(g * 16 + jj) * 68 + d];
      }
      float m = -1e30f;
#pragma unroll
      for (int jj = 0; jj < 16; ++jj) { sv[jj] *= SCALE; m = fmaxf(m, sv[jj]); }
      m = fmaxf(m, __shfl_xor(m, 1));
      m = fmaxf(m, __shfl_xor(m, 2));
      float l = 0.f;
#pragma unroll
      for (int jj = 0; jj < 16; ++jj) { sv[jj] = expf(sv[jj] - m); l += sv[jj]; }
      l += __shfl_xor(l, 1);
      l += __shfl_xor(l, 2);
#pragma unroll
      for (int jj = 0; jj < 16; ++jj) sps[i * 66 + g * 16 + jj] = sv[jj];
      __syncthreads();
      float oa[16];
#pragma unroll
      for (int dd = 0; dd < 16; ++dd) oa[dd] = 0.f;
      for (int j = 0; j < 64; ++j) {
        float pv = sps[i * 66 + j];
#pragma unroll
        for (int dd = 0; dd < 16; ++dd) oa[dd] += pv * vs[j * 68 + g * 16 + dd];
      }
      float invl = 1.0f / l;
      int orow = (base_t + ((i >> 3) << 6) + (i & 7)) * 768 + h * 64 + g * 16;
      unsigned int ow[16];
#pragma unroll
      for (int dd = 0; dd < 16; ++dd) ow[dd] = pack_hl(oa[dd] * invl);
#pragma unroll
      for (int q4 = 0; q4 < 4; ++q4) {
        uint4 w4 = make_uint4(ow[q4 * 4], ow[q4 * 4 + 1], ow[q4 * 4 + 2], ow[q4 * 4 + 3]);
        *(uint4*)(opack + orow + q4 * 4) = w4;
      }
    }
    __syncthreads();
  }
}

// ============ G3: combine global-attn partials -> og_mean (B x 768) ============
__global__ void k_greduce(const float* __restrict__ qkv_g,
                          const float* __restrict__ part,
                          float* __restrict__ og_mean) {
  __shared__ float red[4][64];
  int bh = blockIdx.x;
  int b = bh / 12, h = bh - b * 12;
  int tid = threadIdx.x;
  int qi = tid >> 6, d = tid & 63;
  float M = -1e30f, L = 0.f, A = 0.f;
  float qd = qkv_g[qi * 2304 + h * 64 + d];
#pragma unroll
  for (int gk = 0; gk < 4; ++gk) {
    float kd = qkv_g[gk * 2304 + 768 + h * 64 + d];
    float prod = qd * kd;
#pragma unroll
    for (int o = 1; o < 64; o <<= 1) prod += __shfl_xor(prod, o);
    float s = prod * SCALE;
    float Mn = fmaxf(M, s);
    float f = expf(M - Mn), e = expf(s - Mn);
    float vd = qkv_g[gk * 2304 + 1536 + h * 64 + d];
    A = A * f + e * vd;
    L = L * f + e;
    M = Mn;
  }
  for (int p = 0; p < 64; ++p) {
    int pbase = ((b * 12 + h) * 64 + p) * 272;
    float mp = part[pbase + 256 + qi];
    float lp = part[pbase + 260 + qi];
    float ap = part[pbase + qi * 64 + d];
    float Mn = fmaxf(M, mp);
    float f = expf(M - Mn), e = expf(mp - Mn);
    A = A * f + ap * e;
    L = L * f + lp * e;
    M = Mn;
  }
  red[qi][d] = A / L;
  __syncthreads();
  if (tid < 64) {
    float s = (red[0][d] + red[1][d] + red[2][d] + red[3][d]) * 0.25f;
    og_mean[b * 768 + h * 64 + d] = s;
  }
}

// ============ G4: g_term = og_mean @ w_out (B x 768), fp32 ============
__global__ void k_gterm(const float* __restrict__ og_mean,
                        const float* __restrict__ w_out,
                        float* __restrict__ g_term) {
  int idx = blockIdx.x * 256 + threadIdx.x;   // 0..6143
  int b = idx / 768, c = idx - b * 768;
  const float* op = og_mean + b * 768;
  float s = 0.f;
  for (int d = 0; d < 768; ++d) s += op[d] * w_out[d * 768 + c];
  g_term[idx] = s;
}

// ============ P: out = unpack(opack) @ w_out + g_term  (MFMA, out-of-place) ====
// grid = 512 row-blocks x 4 col-blocks = 2048
__global__ __launch_bounds__(256, 2) void k_proj(
    const unsigned int* __restrict__ opack,
    const unsigned short* __restrict__ Whi,
    const unsigned short* __restrict__ Wlo,
    const float* __restrict__ g_term,
    float* __restrict__ out) {
  __shared__ __align__(16) unsigned short Bst[2][192 * 32];
  const int tid = threadIdx.x;
  const int lane = tid & 63;
  const int wv = tid >> 6;
  const int rblk = blockIdx.x >> 2, cblk = blockIdx.x & 3;
  const int r0 = rblk * 64;
  const int c0 = cblk * 192;
  const int arow = r0 + wv * 16 + (lane & 15);
  const int kb = lane >> 4;
  const unsigned int* aptr = opack + arow * 768 + kb * 8;
  const int bb = r0 >> 12;

  f32x4 acc[12];
#pragma unroll
  for (int t = 0; t < 12; ++t) acc[t] = (f32x4){0.f, 0.f, 0.f, 0.f};

  uint4 breg[6];
#pragma unroll
  for (int e = 0; e < 3; ++e) {
    int idx = e * 256 + tid;
    int c = idx >> 2, u = idx & 3;
    breg[e]     = *(const uint4*)(Whi + (c0 + c) * 768 + u * 8);
    breg[e + 3] = *(const uint4*)(Wlo + (c0 + c) * 768 + u * 8);
  }
  uint4 p0 = *(const uint4*)(aptr);
  uint4 p1 = *(const uint4*)(aptr + 4);

  for (int kc = 0; kc < 24; ++kc) {
#pragma unroll
    for (int e = 0; e < 3; ++e) {
      int idx = e * 256 + tid;
      int c = idx >> 2, u = idx & 3;
      int pu = u ^ ((c >> 1) & 3);
      *(uint4*)&Bst[0][c * 32 + pu * 8] = breg[e];
      *(uint4*)&Bst[1][c * 32 + pu * 8] = breg[e + 3];
    }
    __syncthreads();
    if (kc + 1 < 24) {
#pragma unroll
      for (int e = 0; e < 3; ++e) {
        int idx = e * 256 + tid;
        int c = idx >> 2, u = idx & 3;
        breg[e]     = *(const uint4*)(Whi + (c0 + c) * 768 + (kc + 1) * 32 + u * 8);
        breg[e + 3] = *(const uint4*)(Wlo + (c0 + c) * 768 + (kc + 1) * 32 + u * 8);
      }
    }
    short8 ah, al;
    {
      unsigned int uv[8] = {p0.x, p0.y, p0.z, p0.w, p1.x, p1.y, p1.z, p1.w};
#pragma unroll
      for (int j = 0; j < 8; ++j) {
        ah[j] = (short)(uv[j] >> 16);
        al[j] = (short)(uv[j] & 0xffffu);
      }
    }
    if (kc + 1 < 24) {
      p0 = *(const uint4*)(aptr + (kc + 1) * 32);
      p1 = *(const uint4*)(aptr + (kc + 1) * 32 + 4);
    }
#pragma unroll
    for (int t = 0; t < 12; ++t) {
      int c = t * 16 + (lane & 15);
      int pu = kb ^ ((c >> 1) & 3);
      short8 bh = *(const short8*)&Bst[0][c * 32 + pu * 8];
      short8 bl = *(const short8*)&Bst[1][c * 32 + pu * 8];
      acc[t] = __builtin_amdgcn_mfma_f32_16x16x32_bf16(ah, bh, acc[t], 0, 0, 0);
      acc[t] = __builtin_amdgcn_mfma_f32_16x16x32_bf16(ah, bl, acc[t], 0, 0, 0);
      acc[t] = __builtin_amdgcn_mfma_f32_16x16x32_bf16(al, bh, acc[t], 0, 0, 0);
      acc[t] = __builtin_amdgcn_mfma_f32_16x16x32_bf16(al, bl, acc[t], 0, 0, 0);
    }
    __syncthreads();
  }

#pragma unroll
  for (int t = 0; t < 12; ++t) {
    int col = c0 + t * 16 + (lane & 15);
    float gt = g_term[bb * 768 + col];
    int rb2 = r0 + wv * 16 + (lane >> 4) * 4;
#pragma unroll
    for (int r = 0; r < 4; ++r) out[(rb2 + r) * 768 + col] = acc[t][r] + gt;
  }
}

extern "C" void kernel_launch(void* const* d_in, const int* in_sizes, int n_in,
                              void* d_out, int out_size, void* d_ws, size_t ws_size,
                              hipStream_t stream) {
  const float* x      = (const float*)d_in[0];
  const float* w_qkv  = (const float*)d_in[1];
  const float* w_out  = (const float*)d_in[2];
  const float* qnw    = (const float*)d_in[3];
  const float* knw    = (const float*)d_in[4];
  const float* gtok   = (const float*)d_in[5];
  float* out = (float*)d_out;

  // ---- ws layout (~117 MB) ----
  char* base = (char*)d_ws;
  unsigned short* WhiQ = (unsigned short*)base;            // 2304*768
  unsigned short* WloQ = WhiQ + 2304 * 768;
  unsigned short* WhiO = WloQ + 2304 * 768;                // 768*768
  unsigned short* WloO = WhiO + 768 * 768;
  unsigned int*   opck = (unsigned int*)(WloO + 768 * 768);        // 32768*768
  float* qkv_g   = (float*)(opck + 32768 * 768);           // 9216
  float* part    = qkv_g + 9216;                           // 8*12*64*272
  float* og_mean = part + 8 * 12 * 64 * 272;               // 6144
  float* g_term  = og_mean + 6144;                         // 6144

  k_prep   <<<dim3(36, 12), 256, 0, stream>>>(w_qkv, 2304, 0, WhiQ, WloQ);
  k_prep   <<<dim3(12, 12), 256, 0, stream>>>(w_out,  768, 1, WhiO, WloO);
  k_gqkv   <<<36,   256, 0, stream>>>(gtok, w_qkv, qkv_g);
  k_local  <<<512,  256, 0, stream>>>(x, WhiQ, WloQ, qnw, knw, qkv_g, part, opck);
  k_greduce<<<96,   256, 0, stream>>>(qkv_g, part, og_mean);
  k_gterm  <<<24,   256, 0, stream>>>(og_mean, w_out, g_term);
  k_proj   <<<2048, 256, 0, stream>>>(opck, WhiO, WloO, g_term, out);
}

// Round 3
// 1289.992 us; speedup vs baseline: 2.0199x; 1.4216x over previous
//
#include <hip/hip_runtime.h>
#include <hip/hip_bf16.h>

typedef short short8 __attribute__((ext_vector_type(8)));
typedef unsigned short ushort8 __attribute__((ext_vector_type(8)));
typedef float f32x4 __attribute__((ext_vector_type(4)));
typedef unsigned short ushort;

constexpr float SCALE = 0.125f;   // 64^-0.5
constexpr float EPS_RMS = 1e-6f;

__device__ __forceinline__ ushort f2bf(float f) {
  return __builtin_bit_cast(unsigned short, __float2bfloat16(f));
}
__device__ __forceinline__ float bf2f(ushort u) {
  return __bfloat162float(__builtin_bit_cast(__hip_bfloat16, u));
}
__device__ __forceinline__ void gl_lds16(const void* g, void* l) {
  __builtin_amdgcn_global_load_lds((const __attribute__((address_space(1))) void*)g,
                                   (__attribute__((address_space(3))) void*)l, 16, 0, 0);
}

// permuted row p -> natural token row
__device__ __forceinline__ int nat_row(int p) {
  return (p & ~4095) | (((p >> 9) & 7) << 9) | (((p >> 3) & 7) << 6) |
         (((p >> 6) & 7) << 3) | (p & 7);
}

// ============ P0: transpose + split weights into bf16 hi/lo planes ============
__global__ void k_prep(const float* __restrict__ src, int src_ld, int mode,
                       ushort* __restrict__ hi, ushort* __restrict__ lo) {
  __shared__ float tile[64][65];
  int rb = blockIdx.x, db = blockIdx.y;
  int tid = threadIdx.x;
#pragma unroll
  for (int e = 0; e < 16; ++e) {
    int idx = e * 256 + tid;
    int dd = idx >> 6, cc = idx & 63;
    int sc;
    if (mode == 0) { int h = rb / 3, p = rb % 3; sc = p * 768 + h * 64 + cc; }
    else sc = rb * 64 + cc;
    tile[dd][cc] = src[(db * 64 + dd) * src_ld + sc];
  }
  __syncthreads();
#pragma unroll
  for (int e = 0; e < 16; ++e) {
    int idx = e * 256 + tid;
    int cc = idx >> 6, dd = idx & 63;
    float f = tile[dd][cc];
    ushort h = f2bf(f);
    ushort l = f2bf(f - bf2f(h));
    int o = (rb * 64 + cc) * 768 + db * 64 + dd;
    hi[o] = h;
    lo[o] = l;
  }
}

// ============ X: split x into bf16 hi/lo planes, window-permuted rows ============
__global__ void k_xsplit(const float* __restrict__ x,
                         ushort* __restrict__ xh, ushort* __restrict__ xl) {
  int idx = blockIdx.x * 256 + threadIdx.x;   // 32768*96
  int p = idx / 96, seg = idx - p * 96;
  int n = nat_row(p);
  const float* src = x + n * 768 + seg * 8;
  float4 a = *(const float4*)src;
  float4 c = *(const float4*)(src + 4);
  float v[8] = {a.x, a.y, a.z, a.w, c.x, c.y, c.z, c.w};
  ushort8 hi, lo;
#pragma unroll
  for (int j = 0; j < 8; ++j) {
    ushort h = f2bf(v[j]);
    hi[j] = h;
    lo[j] = f2bf(v[j] - bf2f(h));
  }
  *(ushort8*)&xh[p * 768 + seg * 8] = hi;
  *(ushort8*)&xl[p * 768 + seg * 8] = lo;
}

// ============ G1: QKV of the 4 global tokens (4 x 2304), fp32 ============
__global__ void k_gqkv(const float* __restrict__ gtok,
                       const float* __restrict__ w_qkv,
                       float* __restrict__ qkv_g) {
  int idx = blockIdx.x * 256 + threadIdx.x;   // 0..9215
  int tok = idx / 2304, c = idx - tok * 2304;
  const float* gp = gtok + tok * 768;
  float s = 0.f;
  for (int d = 0; d < 768; ++d) s += gp[d] * w_qkv[d * 2304 + c];
  qkv_g[idx] = s;
}

// ============ GEMM: C[MxN] = A[Mx768] * B^T, 3-term bf16 split ============
// 128x128 tile, BK=32, global_load_lds staging, XOR-swizzled LDS.
// MODE 0: C = qkv_slab (fp32, ldc=2304), local rows.
// MODE 1: C = out (fp32, ldc=768), permuted-row scatter + g_term add.
template<int MODE>
__global__ __launch_bounds__(256, 3) void k_gemm(
    const ushort* __restrict__ Ah, const ushort* __restrict__ Al, int arow0,
    const ushort* __restrict__ Bh, const ushort* __restrict__ Bl,
    float* __restrict__ C, int ldc,
    const float* __restrict__ g_term) {
  __shared__ __align__(16) ushort Ah_s[128 * 32];
  __shared__ __align__(16) ushort Al_s[128 * 32];
  __shared__ __align__(16) ushort Bh_s[128 * 32];
  __shared__ __align__(16) ushort Bl_s[128 * 32];
  const int tid = threadIdx.x, lane = tid & 63, wv = tid >> 6;
  const int r0 = blockIdx.x * 128, c0 = blockIdx.y * 128;

  // staging: chunk c = wv*128 + j*64 + lane -> row=c>>2, slot=c&3,
  // kblk = slot ^ ((row>>1)&3)  (inverse-swizzled global source, linear LDS dest)
  const int rS0 = wv * 32 + (lane >> 2);
  const int sl = lane & 3;
  const int kb0 = sl ^ ((rS0 >> 1) & 3);
  const int rS1 = rS0 + 16;
  const int kb1 = sl ^ ((rS1 >> 1) & 3);
  const int offA0 = (arow0 + r0 + rS0) * 768 + kb0 * 8;
  const int offA1 = (arow0 + r0 + rS1) * 768 + kb1 * 8;
  const int offB0 = (c0 + rS0) * 768 + kb0 * 8;
  const int offB1 = (c0 + rS1) * 768 + kb1 * 8;
  const int d0 = (wv * 128) * 8, d1 = (wv * 128 + 64) * 8;

  const int wr = wv >> 1, wc = wv & 1, l15 = lane & 15, kq = lane >> 4;
  f32x4 acc[4][4] = {};

  for (int kc = 0; kc < 24; ++kc) {
    const int ko = kc * 32;
    gl_lds16(Ah + offA0 + ko, &Ah_s[d0]);
    gl_lds16(Ah + offA1 + ko, &Ah_s[d1]);
    gl_lds16(Al + offA0 + ko, &Al_s[d0]);
    gl_lds16(Al + offA1 + ko, &Al_s[d1]);
    gl_lds16(Bh + offB0 + ko, &Bh_s[d0]);
    gl_lds16(Bh + offB1 + ko, &Bh_s[d1]);
    gl_lds16(Bl + offB0 + ko, &Bl_s[d0]);
    gl_lds16(Bl + offB1 + ko, &Bl_s[d1]);
    __syncthreads();

    short8 ah[4], al[4], bh[4], bl[4];
#pragma unroll
    for (int t = 0; t < 4; ++t) {
      int ra = wr * 64 + t * 16 + l15;
      int sa = (kq ^ ((ra >> 1) & 3)) * 8;
      ah[t] = *(const short8*)&Ah_s[ra * 32 + sa];
      al[t] = *(const short8*)&Al_s[ra * 32 + sa];
      int rb = wc * 64 + t * 16 + l15;
      int sb = (kq ^ ((rb >> 1) & 3)) * 8;
      bh[t] = *(const short8*)&Bh_s[rb * 32 + sb];
      bl[t] = *(const short8*)&Bl_s[rb * 32 + sb];
    }
#pragma unroll
    for (int i = 0; i < 4; ++i)
#pragma unroll
      for (int j = 0; j < 4; ++j) {
        acc[i][j] = __builtin_amdgcn_mfma_f32_16x16x32_bf16(ah[i], bh[j], acc[i][j], 0, 0, 0);
        acc[i][j] = __builtin_amdgcn_mfma_f32_16x16x32_bf16(ah[i], bl[j], acc[i][j], 0, 0, 0);
        acc[i][j] = __builtin_amdgcn_mfma_f32_16x16x32_bf16(al[i], bh[j], acc[i][j], 0, 0, 0);
      }
    __syncthreads();
  }

#pragma unroll
  for (int i = 0; i < 4; ++i)
#pragma unroll
    for (int j = 0; j < 4; ++j) {
      int col = c0 + wc * 64 + j * 16 + l15;
      int rbase = r0 + wr * 64 + i * 16 + kq * 4;
      if (MODE == 0) {
#pragma unroll
        for (int e = 0; e < 4; ++e) C[(rbase + e) * ldc + col] = acc[i][j][e];
      } else {
#pragma unroll
        for (int e = 0; e < 4; ++e) {
          int p = rbase + e;
          float gt = g_term[(p >> 12) * 768 + col];
          C[nat_row(p) * 768 + col] = acc[i][j][e] + gt;
        }
      }
    }
}

// ============ A: per-window attention from qkv slab ============
__global__ __launch_bounds__(256, 2) void k_attn(
    const float* __restrict__ qkv, int wbase,
    const float* __restrict__ qnw, const float* __restrict__ knw,
    const float* __restrict__ qkv_g, float* __restrict__ part,
    ushort* __restrict__ o_hi, ushort* __restrict__ o_lo) {
  __shared__ __align__(16) float qs[64 * 68];
  __shared__ __align__(16) float ks[64 * 68];
  __shared__ __align__(16) float vs[64 * 68];
  __shared__ float sps[64 * 66];
  __shared__ float ps_c[256];

  const int tid = threadIdx.x;
  const int widx = wbase + blockIdx.x;
  const int b = widx >> 6;
  const int wl = widx & 63;
  const int lbase = blockIdx.x * 64 * 2304;

  for (int h = 0; h < 12; ++h) {
    // ---- load q,k,v (fp32) into LDS ----
#pragma unroll
    for (int p = 0; p < 3; ++p) {
      float* dst = (p == 0) ? qs : (p == 1) ? ks : vs;
#pragma unroll
      for (int e = 0; e < 4; ++e) {
        int idx = e * 256 + tid;
        int r = idx >> 4, c4 = idx & 15;
        *(float4*)&dst[r * 68 + c4 * 4] =
            *(const float4*)&qkv[lbase + r * 2304 + h * 192 + p * 64 + c4 * 4];
      }
    }
    __syncthreads();

    // ---- phase C: global-attn partials (raw k,v) ----
    {
      int qi = tid >> 6, j = tid & 63;
      const float* qgp = qkv_g + qi * 2304 + h * 64;
      float s = 0.f;
      for (int d = 0; d < 64; ++d) s += qgp[d] * ks[j * 68 + d];
      s *= SCALE;
      float m = s;
#pragma unroll
      for (int o = 1; o < 64; o <<= 1) m = fmaxf(m, __shfl_xor(m, o));
      float p = expf(s - m);
      float l = p;
#pragma unroll
      for (int o = 1; o < 64; o <<= 1) l += __shfl_xor(l, o);
      ps_c[qi * 64 + j] = p;
      int pbase = ((b * 12 + h) * 64 + wl) * 272;
      if (j == 0) { part[pbase + 256 + qi] = m; part[pbase + 260 + qi] = l; }
      __syncthreads();
      float a = 0.f;
      for (int jj = 0; jj < 64; ++jj) a += ps_c[qi * 64 + jj] * vs[jj * 68 + j];
      part[pbase + qi * 64 + j] = a;
    }

    // ---- rmsnorm(q), rmsnorm(k) in LDS ----
    if (tid < 128) {
      int which = tid >> 6, tk = tid & 63;
      float* row = which ? (ks + tk * 68) : (qs + tk * 68);
      const float* nw = which ? knw : qnw;
      float ss = 0.f;
      for (int d = 0; d < 64; ++d) { float v0 = row[d]; ss += v0 * v0; }
      float sc = 1.0f / sqrtf(ss * 0.015625f + EPS_RMS);
      for (int d = 0; d < 64; ++d) row[d] = row[d] * sc * nw[d];
    }
    __syncthreads();

    // ---- phase B: local attention ----
    {
      int i = tid >> 2, g = tid & 3;
      float sv[16];
#pragma unroll
      for (int jj = 0; jj < 16; ++jj) sv[jj] = 0.f;
      for (int d = 0; d < 64; ++d) {
        float qa = qs[i * 68 + d];
#pragma unroll
        for (int jj = 0; jj < 16; ++jj) sv[jj] += qa * ks[(g * 16 + jj) * 68 + d];
      }
      float m = -1e30f;
#pragma unroll
      for (int jj = 0; jj < 16; ++jj) { sv[jj] *= SCALE; m = fmaxf(m, sv[jj]); }
      m = fmaxf(m, __shfl_xor(m, 1));
      m = fmaxf(m, __shfl_xor(m, 2));
      float l = 0.f;
#pragma unroll
      for (int jj = 0; jj < 16; ++jj) { sv[jj] = expf(sv[jj] - m); l += sv[jj]; }
      l += __shfl_xor(l, 1);
      l += __shfl_xor(l, 2);
#pragma unroll
      for (int jj = 0; jj < 16; ++jj) sps[i * 66 + g * 16 + jj] = sv[jj];
      __syncthreads();
      float oa[16];
#pragma unroll
      for (int dd = 0; dd < 16; ++dd) oa[dd] = 0.f;
      for (int j = 0; j < 64; ++j) {
        float pv = sps[i * 66 + j];
#pragma unroll
        for (int dd = 0; dd < 16; ++dd) oa[dd] += pv * vs[j * 68 + g * 16 + dd];
      }
      float invl = 1.0f / l;
      int orow = (widx * 64 + i) * 768 + h * 64 + g * 16;
      ushort hi[16], lo[16];
#pragma unroll
      for (int dd = 0; dd < 16; ++dd) {
        float vv = oa[dd] * invl;
        hi[dd] = f2bf(vv);
        lo[dd] = f2bf(vv - bf2f(hi[dd]));
      }
      ushort8 h0, h1, l0, l1;
#pragma unroll
      for (int dd = 0; dd < 8; ++dd) {
        h0[dd] = hi[dd]; h1[dd] = hi[dd + 8];
        l0[dd] = lo[dd]; l1[dd] = lo[dd + 8];
      }
      *(ushort8*)&o_hi[orow] = h0;
      *(ushort8*)&o_hi[orow + 8] = h1;
      *(ushort8*)&o_lo[orow] = l0;
      *(ushort8*)&o_lo[orow + 8] = l1;
    }
    __syncthreads();
  }
}

// ============ G3: combine global-attn partials -> og_mean (B x 768) ============
__global__ void k_greduce(const float* __restrict__ qkv_g,
                          const float* __restrict__ part,
                          float* __restrict__ og_mean) {
  __shared__ float red[4][64];
  int bh = blockIdx.x;
  int b = bh / 12, h = bh - b * 12;
  int tid = threadIdx.x;
  int qi = tid >> 6, d = tid & 63;
  float M = -1e30f, L = 0.f, A = 0.f;
  float qd = qkv_g[qi * 2304 + h * 64 + d];
#pragma unroll
  for (int gk = 0; gk < 4; ++gk) {
    float kd = qkv_g[gk * 2304 + 768 + h * 64 + d];
    float prod = qd * kd;
#pragma unroll
    for (int o = 1; o < 64; o <<= 1) prod += __shfl_xor(prod, o);
    float s = prod * SCALE;
    float Mn = fmaxf(M, s);
    float f = expf(M - Mn), e = expf(s - Mn);
    float vd = qkv_g[gk * 2304 + 1536 + h * 64 + d];
    A = A * f + e * vd;
    L = L * f + e;
    M = Mn;
  }
  for (int p = 0; p < 64; ++p) {
    int pbase = ((b * 12 + h) * 64 + p) * 272;
    float mp = part[pbase + 256 + qi];
    float lp = part[pbase + 260 + qi];
    float ap = part[pbase + qi * 64 + d];
    float Mn = fmaxf(M, mp);
    float f = expf(M - Mn), e = expf(mp - Mn);
    A = A * f + ap * e;
    L = L * f + lp * e;
    M = Mn;
  }
  red[qi][d] = A / L;
  __syncthreads();
  if (tid < 64) {
    float s = (red[0][d] + red[1][d] + red[2][d] + red[3][d]) * 0.25f;
    og_mean[b * 768 + h * 64 + d] = s;
  }
}

// ============ G4: g_term = og_mean @ w_out (B x 768), fp32 ============
__global__ void k_gterm(const float* __restrict__ og_mean,
                        const float* __restrict__ w_out,
                        float* __restrict__ g_term) {
  int idx = blockIdx.x * 256 + threadIdx.x;   // 0..6143
  int b = idx / 768, c = idx - b * 768;
  const float* op = og_mean + b * 768;
  float s = 0.f;
  for (int d = 0; d < 768; ++d) s += op[d] * w_out[d * 768 + c];
  g_term[idx] = s;
}

extern "C" void kernel_launch(void* const* d_in, const int* in_sizes, int n_in,
                              void* d_out, int out_size, void* d_ws, size_t ws_size,
                              hipStream_t stream) {
  const float* x      = (const float*)d_in[0];
  const float* w_qkv  = (const float*)d_in[1];
  const float* w_out  = (const float*)d_in[2];
  const float* qnw    = (const float*)d_in[3];
  const float* knw    = (const float*)d_in[4];
  const float* gtok   = (const float*)d_in[5];
  float* out = (float*)d_out;

  // ---- ws layout (~192 MB) ----
  ushort* WhiQ = (ushort*)d_ws;                 // 2304*768
  ushort* WloQ = WhiQ + 2304 * 768;
  ushort* WhiO = WloQ + 2304 * 768;             // 768*768
  ushort* WloO = WhiO + 768 * 768;
  ushort* o_hi = WloO + 768 * 768;              // 32768*768
  ushort* o_lo = o_hi + 32768 * 768;
  float* qkv_slab = (float*)(o_lo + 32768 * 768);   // 8192*2304 fp32 (reused x4)
  float* qkv_g   = qkv_slab + 8192 * 2304;
  float* part    = qkv_g + 9216;                // 8*12*64*272
  float* og_mean = part + 8 * 12 * 64 * 272;
  float* g_term  = og_mean + 6144;

  // x hi/lo planes live in d_out until final projection overwrites it
  ushort* xh = (ushort*)d_out;                  // 32768*768
  ushort* xl = xh + 32768 * 768;

  k_prep  <<<dim3(36, 12), 256, 0, stream>>>(w_qkv, 2304, 0, WhiQ, WloQ);
  k_prep  <<<dim3(12, 12), 256, 0, stream>>>(w_out,  768, 1, WhiO, WloO);
  k_gqkv  <<<36,    256, 0, stream>>>(gtok, w_qkv, qkv_g);
  k_xsplit<<<12288, 256, 0, stream>>>(x, xh, xl);

  for (int s = 0; s < 4; ++s) {
    k_gemm<0><<<dim3(64, 18), 256, 0, stream>>>(xh, xl, s * 8192,
                                                WhiQ, WloQ, qkv_slab, 2304, nullptr);
    k_attn<<<128, 256, 0, stream>>>(qkv_slab, s * 128, qnw, knw, qkv_g, part, o_hi, o_lo);
  }

  k_greduce<<<96, 256, 0, stream>>>(qkv_g, part, og_mean);
  k_gterm  <<<24, 256, 0, stream>>>(og_mean, w_out, g_term);
  k_gemm<1><<<dim3(256, 6), 256, 0, stream>>>(o_hi, o_lo, 0,
                                              WhiO, WloO, out, 768, g_term);
}

// Round 4
// 959.500 us; speedup vs baseline: 2.7157x; 1.3444x over previous
//
#include <hip/hip_runtime.h>
#include <hip/hip_bf16.h>

typedef short short8 __attribute__((ext_vector_type(8)));
typedef unsigned short ushort8 __attribute__((ext_vector_type(8)));
typedef float f32x4 __attribute__((ext_vector_type(4)));
typedef unsigned short ushort;

constexpr float SCALE = 0.125f;   // 64^-0.5
constexpr float EPS_RMS = 1e-6f;

__device__ __forceinline__ ushort f2bf(float f) {
  return __builtin_bit_cast(unsigned short, __float2bfloat16(f));
}
__device__ __forceinline__ float bf2f(ushort u) {
  return __bfloat162float(__builtin_bit_cast(__hip_bfloat16, u));
}
__device__ __forceinline__ void gl_lds16(const void* g, void* l) {
  __builtin_amdgcn_global_load_lds((const __attribute__((address_space(1))) void*)g,
                                   (__attribute__((address_space(3))) void*)l, 16, 0, 0);
}

// permuted row p -> natural token row
__device__ __forceinline__ int nat_row(int p) {
  return (p & ~4095) | (((p >> 9) & 7) << 9) | (((p >> 3) & 7) << 6) |
         (((p >> 6) & 7) << 3) | (p & 7);
}

// ============ P0: transpose + split weights into bf16 hi/lo planes ============
__global__ void k_prep(const float* __restrict__ src, int src_ld, int mode,
                       ushort* __restrict__ hi, ushort* __restrict__ lo) {
  __shared__ float tile[64][65];
  int rb = blockIdx.x, db = blockIdx.y;
  int tid = threadIdx.x;
#pragma unroll
  for (int e = 0; e < 16; ++e) {
    int idx = e * 256 + tid;
    int dd = idx >> 6, cc = idx & 63;
    int sc;
    if (mode == 0) { int h = rb / 3, p = rb % 3; sc = p * 768 + h * 64 + cc; }
    else sc = rb * 64 + cc;
    tile[dd][cc] = src[(db * 64 + dd) * src_ld + sc];
  }
  __syncthreads();
#pragma unroll
  for (int e = 0; e < 16; ++e) {
    int idx = e * 256 + tid;
    int cc = idx >> 6, dd = idx & 63;
    float f = tile[dd][cc];
    ushort h = f2bf(f);
    ushort l = f2bf(f - bf2f(h));
    int o = (rb * 64 + cc) * 768 + db * 64 + dd;
    hi[o] = h;
    lo[o] = l;
  }
}

// ============ X: split x into bf16 hi/lo planes, window-permuted rows ============
__global__ void k_xsplit(const float* __restrict__ x,
                         ushort* __restrict__ xh, ushort* __restrict__ xl) {
  int idx = blockIdx.x * 256 + threadIdx.x;   // 32768*96
  int p = idx / 96, seg = idx - p * 96;
  int n = nat_row(p);
  const float* src = x + n * 768 + seg * 8;
  float4 a = *(const float4*)src;
  float4 c = *(const float4*)(src + 4);
  float v[8] = {a.x, a.y, a.z, a.w, c.x, c.y, c.z, c.w};
  ushort8 hi, lo;
#pragma unroll
  for (int j = 0; j < 8; ++j) {
    ushort h = f2bf(v[j]);
    hi[j] = h;
    lo[j] = f2bf(v[j] - bf2f(h));
  }
  *(ushort8*)&xh[p * 768 + seg * 8] = hi;
  *(ushort8*)&xl[p * 768 + seg * 8] = lo;
}

// ============ G1: QKV of the 4 global tokens (4 x 2304), fp32 ============
__global__ void k_gqkv(const float* __restrict__ gtok,
                       const float* __restrict__ w_qkv,
                       float* __restrict__ qkv_g) {
  int idx = blockIdx.x * 256 + threadIdx.x;   // 0..9215
  int tok = idx / 2304, c = idx - tok * 2304;
  const float* gp = gtok + tok * 768;
  float s = 0.f;
  for (int d = 0; d < 768; ++d) s += gp[d] * w_qkv[d * 2304 + c];
  qkv_g[idx] = s;
}

// ============ GEMM: C[MxN] = A[Mx768] * B^T, 3-term bf16 split ============
template<int MODE>
__global__ __launch_bounds__(256, 3) void k_gemm(
    const ushort* __restrict__ Ah, const ushort* __restrict__ Al, int arow0,
    const ushort* __restrict__ Bh, const ushort* __restrict__ Bl,
    float* __restrict__ C, int ldc,
    const float* __restrict__ g_term) {
  __shared__ __align__(16) ushort Ah_s[128 * 32];
  __shared__ __align__(16) ushort Al_s[128 * 32];
  __shared__ __align__(16) ushort Bh_s[128 * 32];
  __shared__ __align__(16) ushort Bl_s[128 * 32];
  const int tid = threadIdx.x, lane = tid & 63, wv = tid >> 6;
  const int r0 = blockIdx.x * 128, c0 = blockIdx.y * 128;

  const int rS0 = wv * 32 + (lane >> 2);
  const int sl = lane & 3;
  const int kb0 = sl ^ ((rS0 >> 1) & 3);
  const int rS1 = rS0 + 16;
  const int kb1 = sl ^ ((rS1 >> 1) & 3);
  const int offA0 = (arow0 + r0 + rS0) * 768 + kb0 * 8;
  const int offA1 = (arow0 + r0 + rS1) * 768 + kb1 * 8;
  const int offB0 = (c0 + rS0) * 768 + kb0 * 8;
  const int offB1 = (c0 + rS1) * 768 + kb1 * 8;
  const int d0 = (wv * 128) * 8, d1 = (wv * 128 + 64) * 8;

  const int wr = wv >> 1, wc = wv & 1, l15 = lane & 15, kq = lane >> 4;
  f32x4 acc[4][4] = {};

  for (int kc = 0; kc < 24; ++kc) {
    const int ko = kc * 32;
    gl_lds16(Ah + offA0 + ko, &Ah_s[d0]);
    gl_lds16(Ah + offA1 + ko, &Ah_s[d1]);
    gl_lds16(Al + offA0 + ko, &Al_s[d0]);
    gl_lds16(Al + offA1 + ko, &Al_s[d1]);
    gl_lds16(Bh + offB0 + ko, &Bh_s[d0]);
    gl_lds16(Bh + offB1 + ko, &Bh_s[d1]);
    gl_lds16(Bl + offB0 + ko, &Bl_s[d0]);
    gl_lds16(Bl + offB1 + ko, &Bl_s[d1]);
    __syncthreads();

    short8 ah[4], al[4], bh[4], bl[4];
#pragma unroll
    for (int t = 0; t < 4; ++t) {
      int ra = wr * 64 + t * 16 + l15;
      int sa = (kq ^ ((ra >> 1) & 3)) * 8;
      ah[t] = *(const short8*)&Ah_s[ra * 32 + sa];
      al[t] = *(const short8*)&Al_s[ra * 32 + sa];
      int rb = wc * 64 + t * 16 + l15;
      int sb = (kq ^ ((rb >> 1) & 3)) * 8;
      bh[t] = *(const short8*)&Bh_s[rb * 32 + sb];
      bl[t] = *(const short8*)&Bl_s[rb * 32 + sb];
    }
#pragma unroll
    for (int i = 0; i < 4; ++i)
#pragma unroll
      for (int j = 0; j < 4; ++j) {
        acc[i][j] = __builtin_amdgcn_mfma_f32_16x16x32_bf16(ah[i], bh[j], acc[i][j], 0, 0, 0);
        acc[i][j] = __builtin_amdgcn_mfma_f32_16x16x32_bf16(ah[i], bl[j], acc[i][j], 0, 0, 0);
        acc[i][j] = __builtin_amdgcn_mfma_f32_16x16x32_bf16(al[i], bh[j], acc[i][j], 0, 0, 0);
      }
    __syncthreads();
  }

#pragma unroll
  for (int i = 0; i < 4; ++i)
#pragma unroll
    for (int j = 0; j < 4; ++j) {
      int col = c0 + wc * 64 + j * 16 + l15;
      int rbase = r0 + wr * 64 + i * 16 + kq * 4;
      if (MODE == 0) {
#pragma unroll
        for (int e = 0; e < 4; ++e) C[(rbase + e) * ldc + col] = acc[i][j][e];
      } else {
#pragma unroll
        for (int e = 0; e < 4; ++e) {
          int p = rbase + e;
          float gt = g_term[(p >> 12) * 768 + col];
          C[nat_row(p) * 768 + col] = acc[i][j][e] + gt;
        }
      }
    }
}

// ============ A: per-(window,head) attention from qkv slab ============
// grid = 128 windows x 12 heads = 1536 blocks. Pad 67 (odd) -> all hot LDS
// patterns <=2-way. sps aliases qs (q dead after S computed).
__global__ __launch_bounds__(256, 3) void k_attn(
    const float* __restrict__ qkv, int wbase,
    const float* __restrict__ qnw, const float* __restrict__ knw,
    const float* __restrict__ qkv_g, float* __restrict__ part,
    ushort* __restrict__ o_hi, ushort* __restrict__ o_lo) {
  __shared__ float qs[64 * 67];   // aliased as sps in phase B
  __shared__ float ks[64 * 67];
  __shared__ float vs[64 * 67];
  __shared__ float ps_c[256];
  float* sps = qs;

  const int tid = threadIdx.x;
  const int lw = blockIdx.x / 12;
  const int h = blockIdx.x - lw * 12;
  const int widx = wbase + lw;
  const int b = widx >> 6;
  const int wl = widx & 63;
  const int lbase = lw * 64 * 2304 + h * 192;

  // ---- load q,k,v (fp32) into LDS ----
#pragma unroll
  for (int p = 0; p < 3; ++p) {
    float* dst = (p == 0) ? qs : (p == 1) ? ks : vs;
#pragma unroll
    for (int e = 0; e < 4; ++e) {
      int idx = e * 256 + tid;
      int r = idx >> 4, c4 = idx & 15;
      float4 t = *(const float4*)&qkv[lbase + r * 2304 + p * 64 + c4 * 4];
      float* d = &dst[r * 67 + c4 * 4];
      d[0] = t.x; d[1] = t.y; d[2] = t.z; d[3] = t.w;
    }
  }
  __syncthreads();

  // ---- phase C: global-attn partials (raw k,v) ----
  {
    int qi = tid >> 6, j = tid & 63;
    const float* qgp = qkv_g + qi * 2304 + h * 64;
    float s = 0.f;
    for (int d = 0; d < 64; ++d) s += qgp[d] * ks[j * 67 + d];
    s *= SCALE;
    float m = s;
#pragma unroll
    for (int o = 1; o < 64; o <<= 1) m = fmaxf(m, __shfl_xor(m, o));
    float p = expf(s - m);
    float l = p;
#pragma unroll
    for (int o = 1; o < 64; o <<= 1) l += __shfl_xor(l, o);
    ps_c[qi * 64 + j] = p;
    int pbase = ((b * 12 + h) * 64 + wl) * 272;
    if (j == 0) { part[pbase + 256 + qi] = m; part[pbase + 260 + qi] = l; }
    __syncthreads();
    float a = 0.f;
    for (int jj = 0; jj < 64; ++jj) a += ps_c[qi * 64 + jj] * vs[jj * 67 + j];
    part[pbase + qi * 64 + j] = a;
  }

  // ---- rmsnorm(q), rmsnorm(k) in LDS ----
  __syncthreads();
  if (tid < 128) {
    int which = tid >> 6, tk = tid & 63;
    float* row = which ? (ks + tk * 67) : (qs + tk * 67);
    const float* nw = which ? knw : qnw;
    float ss = 0.f;
    for (int d = 0; d < 64; ++d) { float v0 = row[d]; ss += v0 * v0; }
    float sc = 1.0f / sqrtf(ss * 0.015625f + EPS_RMS);
    for (int d = 0; d < 64; ++d) row[d] = row[d] * sc * nw[d];
  }
  __syncthreads();

  // ---- phase B: local attention ----
  {
    int i = tid >> 2, g = tid & 3;
    float sv[16];
#pragma unroll
    for (int jj = 0; jj < 16; ++jj) sv[jj] = 0.f;
    for (int d = 0; d < 64; ++d) {
      float qa = qs[i * 67 + d];
#pragma unroll
      for (int jj = 0; jj < 16; ++jj) sv[jj] += qa * ks[(g * 16 + jj) * 67 + d];
    }
    float m = -1e30f;
#pragma unroll
    for (int jj = 0; jj < 16; ++jj) { sv[jj] *= SCALE; m = fmaxf(m, sv[jj]); }
    m = fmaxf(m, __shfl_xor(m, 1));
    m = fmaxf(m, __shfl_xor(m, 2));
    float l = 0.f;
#pragma unroll
    for (int jj = 0; jj < 16; ++jj) { sv[jj] = expf(sv[jj] - m); l += sv[jj]; }
    l += __shfl_xor(l, 1);
    l += __shfl_xor(l, 2);
    __syncthreads();          // all reads of qs done before sps overwrite
#pragma unroll
    for (int jj = 0; jj < 16; ++jj) sps[i * 67 + g * 16 + jj] = sv[jj];
    __syncthreads();
    float oa[16];
#pragma unroll
    for (int dd = 0; dd < 16; ++dd) oa[dd] = 0.f;
    for (int j = 0; j < 64; ++j) {
      float pv = sps[i * 67 + j];
#pragma unroll
      for (int dd = 0; dd < 16; ++dd) oa[dd] += pv * vs[j * 67 + g * 16 + dd];
    }
    float invl = 1.0f / l;
    int orow = (widx * 64 + i) * 768 + h * 64 + g * 16;
    ushort hi[16], lo[16];
#pragma unroll
    for (int dd = 0; dd < 16; ++dd) {
      float vv = oa[dd] * invl;
      hi[dd] = f2bf(vv);
      lo[dd] = f2bf(vv - bf2f(hi[dd]));
    }
    ushort8 h0, h1, l0, l1;
#pragma unroll
    for (int dd = 0; dd < 8; ++dd) {
      h0[dd] = hi[dd]; h1[dd] = hi[dd + 8];
      l0[dd] = lo[dd]; l1[dd] = lo[dd + 8];
    }
    *(ushort8*)&o_hi[orow] = h0;
    *(ushort8*)&o_hi[orow + 8] = h1;
    *(ushort8*)&o_lo[orow] = l0;
    *(ushort8*)&o_lo[orow + 8] = l1;
  }
}

// ============ G3: combine global-attn partials -> og_mean (B x 768) ============
__global__ void k_greduce(const float* __restrict__ qkv_g,
                          const float* __restrict__ part,
                          float* __restrict__ og_mean) {
  __shared__ float red[4][64];
  int bh = blockIdx.x;
  int b = bh / 12, h = bh - b * 12;
  int tid = threadIdx.x;
  int qi = tid >> 6, d = tid & 63;
  float M = -1e30f, L = 0.f, A = 0.f;
  float qd = qkv_g[qi * 2304 + h * 64 + d];
#pragma unroll
  for (int gk = 0; gk < 4; ++gk) {
    float kd = qkv_g[gk * 2304 + 768 + h * 64 + d];
    float prod = qd * kd;
#pragma unroll
    for (int o = 1; o < 64; o <<= 1) prod += __shfl_xor(prod, o);
    float s = prod * SCALE;
    float Mn = fmaxf(M, s);
    float f = expf(M - Mn), e = expf(s - Mn);
    float vd = qkv_g[gk * 2304 + 1536 + h * 64 + d];
    A = A * f + e * vd;
    L = L * f + e;
    M = Mn;
  }
  for (int p = 0; p < 64; ++p) {
    int pbase = ((b * 12 + h) * 64 + p) * 272;
    float mp = part[pbase + 256 + qi];
    float lp = part[pbase + 260 + qi];
    float ap = part[pbase + qi * 64 + d];
    float Mn = fmaxf(M, mp);
    float f = expf(M - Mn), e = expf(mp - Mn);
    A = A * f + ap * e;
    L = L * f + lp * e;
    M = Mn;
  }
  red[qi][d] = A / L;
  __syncthreads();
  if (tid < 64) {
    float s = (red[0][d] + red[1][d] + red[2][d] + red[3][d]) * 0.25f;
    og_mean[b * 768 + h * 64 + d] = s;
  }
}

// ============ G4: g_term = og_mean @ w_out (B x 768), fp32 ============
__global__ void k_gterm(const float* __restrict__ og_mean,
                        const float* __restrict__ w_out,
                        float* __restrict__ g_term) {
  int idx = blockIdx.x * 256 + threadIdx.x;   // 0..6143
  int b = idx / 768, c = idx - b * 768;
  const float* op = og_mean + b * 768;
  float s = 0.f;
  for (int d = 0; d < 768; ++d) s += op[d] * w_out[d * 768 + c];
  g_term[idx] = s;
}

extern "C" void kernel_launch(void* const* d_in, const int* in_sizes, int n_in,
                              void* d_out, int out_size, void* d_ws, size_t ws_size,
                              hipStream_t stream) {
  const float* x      = (const float*)d_in[0];
  const float* w_qkv  = (const float*)d_in[1];
  const float* w_out  = (const float*)d_in[2];
  const float* qnw    = (const float*)d_in[3];
  const float* knw    = (const float*)d_in[4];
  const float* gtok   = (const float*)d_in[5];
  float* out = (float*)d_out;

  // ---- ws layout (~192 MB) ----
  ushort* WhiQ = (ushort*)d_ws;                 // 2304*768
  ushort* WloQ = WhiQ + 2304 * 768;
  ushort* WhiO = WloQ + 2304 * 768;             // 768*768
  ushort* WloO = WhiO + 768 * 768;
  ushort* o_hi = WloO + 768 * 768;              // 32768*768
  ushort* o_lo = o_hi + 32768 * 768;
  float* qkv_slab = (float*)(o_lo + 32768 * 768);   // 8192*2304 fp32 (reused x4)
  float* qkv_g   = qkv_slab + 8192 * 2304;
  float* part    = qkv_g + 9216;                // 8*12*64*272
  float* og_mean = part + 8 * 12 * 64 * 272;
  float* g_term  = og_mean + 6144;

  // x hi/lo planes live in d_out until final projection overwrites it
  ushort* xh = (ushort*)d_out;                  // 32768*768
  ushort* xl = xh + 32768 * 768;

  k_prep  <<<dim3(36, 12), 256, 0, stream>>>(w_qkv, 2304, 0, WhiQ, WloQ);
  k_prep  <<<dim3(12, 12), 256, 0, stream>>>(w_out,  768, 1, WhiO, WloO);
  k_gqkv  <<<36,    256, 0, stream>>>(gtok, w_qkv, qkv_g);
  k_xsplit<<<12288, 256, 0, stream>>>(x, xh, xl);

  for (int s = 0; s < 4; ++s) {
    k_gemm<0><<<dim3(64, 18), 256, 0, stream>>>(xh, xl, s * 8192,
                                                WhiQ, WloQ, qkv_slab, 2304, nullptr);
    k_attn<<<1536, 256, 0, stream>>>(qkv_slab, s * 128, qnw, knw, qkv_g, part, o_hi, o_lo);
  }

  k_greduce<<<96, 256, 0, stream>>>(qkv_g, part, og_mean);
  k_gterm  <<<24, 256, 0, stream>>>(og_mean, w_out, g_term);
  k_gemm<1><<<dim3(256, 6), 256, 0, stream>>>(o_hi, o_lo, 0,
                                              WhiO, WloO, out, 768, g_term);
}

// Round 5
// 902.159 us; speedup vs baseline: 2.8883x; 1.0636x over previous
//
#include <hip/hip_runtime.h>
#include <hip/hip_bf16.h>

typedef short short8 __attribute__((ext_vector_type(8)));
typedef unsigned short ushort8 __attribute__((ext_vector_type(8)));
typedef float f32x4 __attribute__((ext_vector_type(4)));
typedef unsigned short ushort;

constexpr float SCALE = 0.125f;   // 64^-0.5
constexpr float EPS_RMS = 1e-6f;

#define BAR() asm volatile("s_barrier" ::: "memory")
#define WAITV(N) asm volatile("s_waitcnt vmcnt(" #N ")" ::: "memory")

__device__ __forceinline__ ushort f2bf(float f) {
  return __builtin_bit_cast(unsigned short, __float2bfloat16(f));
}
__device__ __forceinline__ float bf2f(ushort u) {
  return __bfloat162float(__builtin_bit_cast(__hip_bfloat16, u));
}
__device__ __forceinline__ void gl_lds16(const void* g, void* l) {
  __builtin_amdgcn_global_load_lds((const __attribute__((address_space(1))) void*)g,
                                   (__attribute__((address_space(3))) void*)l, 16, 0, 0);
}

// permuted row p -> natural token row
__device__ __forceinline__ int nat_row(int p) {
  return (p & ~4095) | (((p >> 9) & 7) << 9) | (((p >> 3) & 7) << 6) |
         (((p >> 6) & 7) << 3) | (p & 7);
}

// ============ P0: transpose + split weights into bf16 hi/lo planes ============
__global__ void k_prep(const float* __restrict__ src, int src_ld, int mode,
                       ushort* __restrict__ hi, ushort* __restrict__ lo) {
  __shared__ float tile[64][65];
  int rb = blockIdx.x, db = blockIdx.y;
  int tid = threadIdx.x;
#pragma unroll
  for (int e = 0; e < 16; ++e) {
    int idx = e * 256 + tid;
    int dd = idx >> 6, cc = idx & 63;
    int sc;
    if (mode == 0) { int h = rb / 3, p = rb % 3; sc = p * 768 + h * 64 + cc; }
    else sc = rb * 64 + cc;
    tile[dd][cc] = src[(db * 64 + dd) * src_ld + sc];
  }
  __syncthreads();
#pragma unroll
  for (int e = 0; e < 16; ++e) {
    int idx = e * 256 + tid;
    int cc = idx >> 6, dd = idx & 63;
    float f = tile[dd][cc];
    ushort h = f2bf(f);
    ushort l = f2bf(f - bf2f(h));
    int o = (rb * 64 + cc) * 768 + db * 64 + dd;
    hi[o] = h;
    lo[o] = l;
  }
}

// ============ X: split x into bf16 hi/lo planes, window-permuted rows ============
__global__ void k_xsplit(const float* __restrict__ x,
                         ushort* __restrict__ xh, ushort* __restrict__ xl) {
  int idx = blockIdx.x * 256 + threadIdx.x;   // 32768*96
  int p = idx / 96, seg = idx - p * 96;
  int n = nat_row(p);
  const float* src = x + n * 768 + seg * 8;
  float4 a = *(const float4*)src;
  float4 c = *(const float4*)(src + 4);
  float v[8] = {a.x, a.y, a.z, a.w, c.x, c.y, c.z, c.w};
  ushort8 hi, lo;
#pragma unroll
  for (int j = 0; j < 8; ++j) {
    ushort h = f2bf(v[j]);
    hi[j] = h;
    lo[j] = f2bf(v[j] - bf2f(h));
  }
  *(ushort8*)&xh[p * 768 + seg * 8] = hi;
  *(ushort8*)&xl[p * 768 + seg * 8] = lo;
}

// ============ G1: QKV of the 4 global tokens (4 x 2304), fp32 ============
__global__ void k_gqkv(const float* __restrict__ gtok,
                       const float* __restrict__ w_qkv,
                       float* __restrict__ qkv_g) {
  int idx = blockIdx.x * 256 + threadIdx.x;   // 0..9215
  int tok = idx / 2304, c = idx - tok * 2304;
  const float* gp = gtok + tok * 768;
  float s = 0.f;
  for (int d = 0; d < 768; ++d) s += gp[d] * w_qkv[d * 2304 + c];
  qkv_g[idx] = s;
}

// ============ F: fused QKV-GEMM (256x192 tile, pipelined) + attention ============
// grid = 128 mblk x 12 heads. 512 threads = 8 waves (4M x 2N), wave tile 64x96.
// K-concat 36 tiles of BK=64: t<12:(Ah,Bh) 12<=t<24:(Ah,Bl) t>=24:(Al,Bh).
__global__ __launch_bounds__(512, 2) void k_fused(
    const ushort* __restrict__ xh, const ushort* __restrict__ xl,
    const ushort* __restrict__ Whi, const ushort* __restrict__ Wlo,
    const float* __restrict__ qnw, const float* __restrict__ knw,
    const float* __restrict__ qkv_g, float* __restrict__ part,
    ushort* __restrict__ o_hi, ushort* __restrict__ o_lo) {
  __shared__ __align__(16) char smem[114688];   // 2 x (A 32KB + B 24KB)
  const int tid = threadIdx.x;
  const int lane = tid & 63;
  const int wv = tid >> 6;
  const int wm = wv >> 1, wn = wv & 1;          // 4M x 2N
  const int l15 = lane & 15, kq = lane >> 4, ln7 = lane & 7;
  const int mblk = blockIdx.x / 12;
  const int h = blockIdx.x - mblk * 12;
  const int r0 = mblk * 256;
  const int cb0 = h * 192;

  int gA[4], lA[4], gB[3], lB[3];
#pragma unroll
  for (int j = 0; j < 4; ++j) {
    int c = j * 512 + tid; int row = c >> 3, sl = c & 7;
    gA[j] = (r0 + row) * 768 + ((sl ^ (row & 7)) << 3); lA[j] = c << 4;
  }
#pragma unroll
  for (int j = 0; j < 3; ++j) {
    int c = j * 512 + tid; int row = c >> 3, sl = c & 7;
    gB[j] = (cb0 + row) * 768 + ((sl ^ (row & 7)) << 3); lB[j] = 32768 + (c << 4);
  }

  f32x4 acc[4][6];
#pragma unroll
  for (int i = 0; i < 4; ++i)
#pragma unroll
    for (int j = 0; j < 6; ++j) acc[i][j] = (f32x4){0.f, 0.f, 0.f, 0.f};

  auto STAGE = [&](int t, int bufi) {
    const ushort* Ap = (t < 24) ? xh : xl;
    const ushort* Bp = (t >= 12 && t < 24) ? Wlo : Whi;
    int seg = (t >= 24) ? (t - 24) : (t >= 12) ? (t - 12) : t;
    int kk = seg << 6;
    char* bb = smem + bufi * 57344;
#pragma unroll
    for (int j = 0; j < 4; ++j) gl_lds16(Ap + gA[j] + kk, bb + lA[j]);
#pragma unroll
    for (int j = 0; j < 3; ++j) gl_lds16(Bp + gB[j] + kk, bb + lB[j]);
  };

  auto COMPUTE = [&](int bufi) {
    const char* ba = smem + bufi * 57344;
    const char* bbp = ba + 32768;
#pragma unroll
    for (int ks = 0; ks < 2; ++ks) {
      const int so = (((ks << 2) | kq) ^ ln7) << 4;
      short8 a[4], b[6];
#pragma unroll
      for (int mf = 0; mf < 4; ++mf)
        a[mf] = *(const short8*)(ba + (wm * 64 + mf * 16 + l15) * 128 + so);
#pragma unroll
      for (int nf = 0; nf < 6; ++nf)
        b[nf] = *(const short8*)(bbp + (wn * 96 + nf * 16 + l15) * 128 + so);
#pragma unroll
      for (int mf = 0; mf < 4; ++mf)
#pragma unroll
        for (int nf = 0; nf < 6; ++nf)
          acc[mf][nf] = __builtin_amdgcn_mfma_f32_16x16x32_bf16(a[mf], b[nf], acc[mf][nf], 0, 0, 0);
    }
  };

  STAGE(0, 0); STAGE(1, 1);
  WAITV(7); BAR();
  for (int t = 0; t < 36; ++t) {
    int cur = t & 1;
    COMPUTE(cur);
    BAR();
    if (t < 34) { STAGE(t + 2, cur); WAITV(7); }
    else { WAITV(0); }
    BAR();
  }

  // ======== attention: 2 passes x 2 windows; per-window 256-thread groups ========
  const int g = tid >> 8, tl = tid & 255;
  for (int pass = 0; pass < 2; ++pass) {
    // scatter this pass's windows (waves with wm in {2p, 2p+1}) to LDS
    if ((wm >> 1) == pass) {
      char* wb = smem + (wm & 1) * 52480;
#pragma unroll
      for (int mf = 0; mf < 4; ++mf) {
        int tok = mf * 16 + kq * 4;
#pragma unroll
        for (int nf = 0; nf < 6; ++nf) {
          int col = wn * 96 + nf * 16 + l15;
          int pp = col >> 6, d = col & 63;
          float* dst = (float*)(wb + pp * 17152);
#pragma unroll
          for (int e = 0; e < 4; ++e) dst[(tok + e) * 67 + d] = acc[mf][nf][e];
        }
      }
    }
    __syncthreads();

    float* qs = (float*)(smem + g * 52480);
    float* ks = qs + 4288;
    float* vs = qs + 8576;
    float* ps_c = qs + 12864;
    float* sps = qs;
    const int widx = mblk * 4 + pass * 2 + g;
    const int b = widx >> 6, wl = widx & 63;

    // ---- phase C: global-attn partials (raw k,v) ----
    {
      int qi = tl >> 6, j = tl & 63;
      const float* qgp = qkv_g + qi * 2304 + h * 64;
      float s = 0.f;
      for (int d = 0; d < 64; ++d) s += qgp[d] * ks[j * 67 + d];
      s *= SCALE;
      float m = s;
#pragma unroll
      for (int o = 1; o < 64; o <<= 1) m = fmaxf(m, __shfl_xor(m, o));
      float p = expf(s - m);
      float l = p;
#pragma unroll
      for (int o = 1; o < 64; o <<= 1) l += __shfl_xor(l, o);
      ps_c[qi * 64 + j] = p;
      int pbase = ((b * 12 + h) * 64 + wl) * 272;
      if (j == 0) { part[pbase + 256 + qi] = m; part[pbase + 260 + qi] = l; }
      __syncthreads();
      float a = 0.f;
      for (int jj = 0; jj < 64; ++jj) a += ps_c[qi * 64 + jj] * vs[jj * 67 + j];
      part[pbase + qi * 64 + j] = a;
    }

    // ---- rmsnorm(q), rmsnorm(k) ----
    __syncthreads();
    if (tl < 128) {
      int which = tl >> 6, tk = tl & 63;
      float* row = which ? (ks + tk * 67) : (qs + tk * 67);
      const float* nw = which ? knw : qnw;
      float ss = 0.f;
      for (int d = 0; d < 64; ++d) { float v0 = row[d]; ss += v0 * v0; }
      float sc = 1.0f / sqrtf(ss * 0.015625f + EPS_RMS);
      for (int d = 0; d < 64; ++d) row[d] = row[d] * sc * nw[d];
    }
    __syncthreads();

    // ---- phase B: local attention ----
    {
      int i = tl >> 2, g16 = tl & 3;
      float sv[16];
#pragma unroll
      for (int jj = 0; jj < 16; ++jj) sv[jj] = 0.f;
      for (int d = 0; d < 64; ++d) {
        float qa = qs[i * 67 + d];
#pragma unroll
        for (int jj = 0; jj < 16; ++jj) sv[jj] += qa * ks[(g16 * 16 + jj) * 67 + d];
      }
      float m = -1e30f;
#pragma unroll
      for (int jj = 0; jj < 16; ++jj) { sv[jj] *= SCALE; m = fmaxf(m, sv[jj]); }
      m = fmaxf(m, __shfl_xor(m, 1));
      m = fmaxf(m, __shfl_xor(m, 2));
      float l = 0.f;
#pragma unroll
      for (int jj = 0; jj < 16; ++jj) { sv[jj] = expf(sv[jj] - m); l += sv[jj]; }
      l += __shfl_xor(l, 1);
      l += __shfl_xor(l, 2);
      __syncthreads();          // all reads of qs done before sps overwrite
#pragma unroll
      for (int jj = 0; jj < 16; ++jj) sps[i * 67 + g16 * 16 + jj] = sv[jj];
      __syncthreads();
      float oa[16];
#pragma unroll
      for (int dd = 0; dd < 16; ++dd) oa[dd] = 0.f;
      for (int j = 0; j < 64; ++j) {
        float pv = sps[i * 67 + j];
#pragma unroll
        for (int dd = 0; dd < 16; ++dd) oa[dd] += pv * vs[j * 67 + g16 * 16 + dd];
      }
      float invl = 1.0f / l;
      int orow = (widx * 64 + i) * 768 + h * 64 + g16 * 16;
      ushort hi[16], lo[16];
#pragma unroll
      for (int dd = 0; dd < 16; ++dd) {
        float vv = oa[dd] * invl;
        hi[dd] = f2bf(vv);
        lo[dd] = f2bf(vv - bf2f(hi[dd]));
      }
      ushort8 h0, h1, l0, l1;
#pragma unroll
      for (int dd = 0; dd < 8; ++dd) {
        h0[dd] = hi[dd]; h1[dd] = hi[dd + 8];
        l0[dd] = lo[dd]; l1[dd] = lo[dd + 8];
      }
      *(ushort8*)&o_hi[orow] = h0;
      *(ushort8*)&o_hi[orow + 8] = h1;
      *(ushort8*)&o_lo[orow] = l0;
      *(ushort8*)&o_lo[orow + 8] = l1;
    }
    __syncthreads();
  }
}

// ============ P: projection out = o @ w_out + g_term (256x192 tile, pipelined) ====
// grid = 128 mblk x 4 cblk.
__global__ __launch_bounds__(512, 2) void k_proj8(
    const ushort* __restrict__ o_hi, const ushort* __restrict__ o_lo,
    const ushort* __restrict__ Whi, const ushort* __restrict__ Wlo,
    const float* __restrict__ g_term, float* __restrict__ out) {
  __shared__ __align__(16) char smem[114688];
  const int tid = threadIdx.x;
  const int lane = tid & 63;
  const int wv = tid >> 6;
  const int wm = wv >> 1, wn = wv & 1;
  const int l15 = lane & 15, kq = lane >> 4, ln7 = lane & 7;
  const int mblk = blockIdx.x >> 2;
  const int cblk = blockIdx.x & 3;
  const int r0 = mblk * 256;
  const int cb0 = cblk * 192;

  int gA[4], lA[4], gB[3], lB[3];
#pragma unroll
  for (int j = 0; j < 4; ++j) {
    int c = j * 512 + tid; int row = c >> 3, sl = c & 7;
    gA[j] = (r0 + row) * 768 + ((sl ^ (row & 7)) << 3); lA[j] = c << 4;
  }
#pragma unroll
  for (int j = 0; j < 3; ++j) {
    int c = j * 512 + tid; int row = c >> 3, sl = c & 7;
    gB[j] = (cb0 + row) * 768 + ((sl ^ (row & 7)) << 3); lB[j] = 32768 + (c << 4);
  }

  f32x4 acc[4][6];
#pragma unroll
  for (int i = 0; i < 4; ++i)
#pragma unroll
    for (int j = 0; j < 6; ++j) acc[i][j] = (f32x4){0.f, 0.f, 0.f, 0.f};

  auto STAGE = [&](int t, int bufi) {
    const ushort* Ap = (t < 24) ? o_hi : o_lo;
    const ushort* Bp = (t >= 12 && t < 24) ? Wlo : Whi;
    int seg = (t >= 24) ? (t - 24) : (t >= 12) ? (t - 12) : t;
    int kk = seg << 6;
    char* bb = smem + bufi * 57344;
#pragma unroll
    for (int j = 0; j < 4; ++j) gl_lds16(Ap + gA[j] + kk, bb + lA[j]);
#pragma unroll
    for (int j = 0; j < 3; ++j) gl_lds16(Bp + gB[j] + kk, bb + lB[j]);
  };

  auto COMPUTE = [&](int bufi) {
    const char* ba = smem + bufi * 57344;
    const char* bbp = ba + 32768;
#pragma unroll
    for (int ks = 0; ks < 2; ++ks) {
      const int so = (((ks << 2) | kq) ^ ln7) << 4;
      short8 a[4], b[6];
#pragma unroll
      for (int mf = 0; mf < 4; ++mf)
        a[mf] = *(const short8*)(ba + (wm * 64 + mf * 16 + l15) * 128 + so);
#pragma unroll
      for (int nf = 0; nf < 6; ++nf)
        b[nf] = *(const short8*)(bbp + (wn * 96 + nf * 16 + l15) * 128 + so);
#pragma unroll
      for (int mf = 0; mf < 4; ++mf)
#pragma unroll
        for (int nf = 0; nf < 6; ++nf)
          acc[mf][nf] = __builtin_amdgcn_mfma_f32_16x16x32_bf16(a[mf], b[nf], acc[mf][nf], 0, 0, 0);
    }
  };

  STAGE(0, 0); STAGE(1, 1);
  WAITV(7); BAR();
  for (int t = 0; t < 36; ++t) {
    int cur = t & 1;
    COMPUTE(cur);
    BAR();
    if (t < 34) { STAGE(t + 2, cur); WAITV(7); }
    else { WAITV(0); }
    BAR();
  }

#pragma unroll
  for (int mf = 0; mf < 4; ++mf) {
    int prow0 = r0 + wm * 64 + mf * 16 + kq * 4;
#pragma unroll
    for (int nf = 0; nf < 6; ++nf) {
      int col = cb0 + wn * 96 + nf * 16 + l15;
#pragma unroll
      for (int e = 0; e < 4; ++e) {
        int p = prow0 + e;
        out[nat_row(p) * 768 + col] = acc[mf][nf][e] + g_term[(p >> 12) * 768 + col];
      }
    }
  }
}

// ============ G3: combine global-attn partials -> og_mean (B x 768) ============
__global__ void k_greduce(const float* __restrict__ qkv_g,
                          const float* __restrict__ part,
                          float* __restrict__ og_mean) {
  __shared__ float red[4][64];
  int bh = blockIdx.x;
  int b = bh / 12, h = bh - b * 12;
  int tid = threadIdx.x;
  int qi = tid >> 6, d = tid & 63;
  float M = -1e30f, L = 0.f, A = 0.f;
  float qd = qkv_g[qi * 2304 + h * 64 + d];
#pragma unroll
  for (int gk = 0; gk < 4; ++gk) {
    float kd = qkv_g[gk * 2304 + 768 + h * 64 + d];
    float prod = qd * kd;
#pragma unroll
    for (int o = 1; o < 64; o <<= 1) prod += __shfl_xor(prod, o);
    float s = prod * SCALE;
    float Mn = fmaxf(M, s);
    float f = expf(M - Mn), e = expf(s - Mn);
    float vd = qkv_g[gk * 2304 + 1536 + h * 64 + d];
    A = A * f + e * vd;
    L = L * f + e;
    M = Mn;
  }
  for (int p = 0; p < 64; ++p) {
    int pbase = ((b * 12 + h) * 64 + p) * 272;
    float mp = part[pbase + 256 + qi];
    float lp = part[pbase + 260 + qi];
    float ap = part[pbase + qi * 64 + d];
    float Mn = fmaxf(M, mp);
    float f = expf(M - Mn), e = expf(mp - Mn);
    A = A * f + ap * e;
    L = L * f + lp * e;
    M = Mn;
  }
  red[qi][d] = A / L;
  __syncthreads();
  if (tid < 64) {
    float s = (red[0][d] + red[1][d] + red[2][d] + red[3][d]) * 0.25f;
    og_mean[b * 768 + h * 64 + d] = s;
  }
}

// ============ G4: g_term = og_mean @ w_out (B x 768), fp32 ============
__global__ void k_gterm(const float* __restrict__ og_mean,
                        const float* __restrict__ w_out,
                        float* __restrict__ g_term) {
  int idx = blockIdx.x * 256 + threadIdx.x;   // 0..6143
  int b = idx / 768, c = idx - b * 768;
  const float* op = og_mean + b * 768;
  float s = 0.f;
  for (int d = 0; d < 768; ++d) s += op[d] * w_out[d * 768 + c];
  g_term[idx] = s;
}

extern "C" void kernel_launch(void* const* d_in, const int* in_sizes, int n_in,
                              void* d_out, int out_size, void* d_ws, size_t ws_size,
                              hipStream_t stream) {
  const float* x      = (const float*)d_in[0];
  const float* w_qkv  = (const float*)d_in[1];
  const float* w_out  = (const float*)d_in[2];
  const float* qnw    = (const float*)d_in[3];
  const float* knw    = (const float*)d_in[4];
  const float* gtok   = (const float*)d_in[5];
  float* out = (float*)d_out;

  // ---- ws layout (~117 MB) ----
  ushort* WhiQ = (ushort*)d_ws;                 // 2304*768
  ushort* WloQ = WhiQ + 2304 * 768;
  ushort* WhiO = WloQ + 2304 * 768;             // 768*768
  ushort* WloO = WhiO + 768 * 768;
  ushort* o_hi = WloO + 768 * 768;              // 32768*768
  ushort* o_lo = o_hi + 32768 * 768;
  float* qkv_g   = (float*)(o_lo + 32768 * 768);
  float* part    = qkv_g + 9216;                // 8*12*64*272
  float* og_mean = part + 8 * 12 * 64 * 272;
  float* g_term  = og_mean + 6144;

  // x hi/lo planes live in d_out until the final projection overwrites it
  ushort* xh = (ushort*)d_out;                  // 32768*768
  ushort* xl = xh + 32768 * 768;

  k_prep  <<<dim3(36, 12), 256, 0, stream>>>(w_qkv, 2304, 0, WhiQ, WloQ);
  k_prep  <<<dim3(12, 12), 256, 0, stream>>>(w_out,  768, 1, WhiO, WloO);
  k_gqkv  <<<36,    256, 0, stream>>>(gtok, w_qkv, qkv_g);
  k_xsplit<<<12288, 256, 0, stream>>>(x, xh, xl);

  k_fused <<<1536, 512, 0, stream>>>(xh, xl, WhiQ, WloQ, qnw, knw, qkv_g, part, o_hi, o_lo);

  k_greduce<<<96, 256, 0, stream>>>(qkv_g, part, og_mean);
  k_gterm  <<<24, 256, 0, stream>>>(og_mean, w_out, g_term);
  k_proj8 <<<512, 512, 0, stream>>>(o_hi, o_lo, WhiO, WloO, g_term, out);
}

// Round 6
// 885.153 us; speedup vs baseline: 2.9438x; 1.0192x over previous
//
#include <hip/hip_runtime.h>
#include <hip/hip_bf16.h>

typedef short short8 __attribute__((ext_vector_type(8)));
typedef unsigned short ushort8 __attribute__((ext_vector_type(8)));
typedef float f32x4 __attribute__((ext_vector_type(4)));
typedef unsigned short ushort;

constexpr float SCALE = 0.125f;   // 64^-0.5
constexpr float EPS_RMS = 1e-6f;

#define BAR() asm volatile("s_barrier" ::: "memory")
#define WAITV(N) asm volatile("s_waitcnt vmcnt(" #N ")" ::: "memory")

__device__ __forceinline__ ushort f2bf(float f) {
  return __builtin_bit_cast(unsigned short, __float2bfloat16(f));
}
__device__ __forceinline__ float bf2f(ushort u) {
  return __bfloat162float(__builtin_bit_cast(__hip_bfloat16, u));
}
__device__ __forceinline__ void gl_lds16(const void* g, void* l) {
  __builtin_amdgcn_global_load_lds((const __attribute__((address_space(1))) void*)g,
                                   (__attribute__((address_space(3))) void*)l, 16, 0, 0);
}

// permuted row p -> natural token row
__device__ __forceinline__ int nat_row(int p) {
  return (p & ~4095) | (((p >> 9) & 7) << 9) | (((p >> 3) & 7) << 6) |
         (((p >> 6) & 7) << 3) | (p & 7);
}

// ============ P0: transpose + split weights into bf16 hi/lo planes ============
__global__ void k_prep(const float* __restrict__ src, int src_ld, int mode,
                       ushort* __restrict__ hi, ushort* __restrict__ lo) {
  __shared__ float tile[64][65];
  int rb = blockIdx.x, db = blockIdx.y;
  int tid = threadIdx.x;
#pragma unroll
  for (int e = 0; e < 16; ++e) {
    int idx = e * 256 + tid;
    int dd = idx >> 6, cc = idx & 63;
    int sc;
    if (mode == 0) { int h = rb / 3, p = rb % 3; sc = p * 768 + h * 64 + cc; }
    else sc = rb * 64 + cc;
    tile[dd][cc] = src[(db * 64 + dd) * src_ld + sc];
  }
  __syncthreads();
#pragma unroll
  for (int e = 0; e < 16; ++e) {
    int idx = e * 256 + tid;
    int cc = idx >> 6, dd = idx & 63;
    float f = tile[dd][cc];
    ushort h = f2bf(f);
    ushort l = f2bf(f - bf2f(h));
    int o = (rb * 64 + cc) * 768 + db * 64 + dd;
    hi[o] = h;
    lo[o] = l;
  }
}

// ============ X: split x into bf16 hi/lo planes, window-permuted rows ============
__global__ void k_xsplit(const float* __restrict__ x,
                         ushort* __restrict__ xh, ushort* __restrict__ xl) {
  int idx = blockIdx.x * 256 + threadIdx.x;   // 32768*96
  int p = idx / 96, seg = idx - p * 96;
  int n = nat_row(p);
  const float* src = x + n * 768 + seg * 8;
  float4 a = *(const float4*)src;
  float4 c = *(const float4*)(src + 4);
  float v[8] = {a.x, a.y, a.z, a.w, c.x, c.y, c.z, c.w};
  ushort8 hi, lo;
#pragma unroll
  for (int j = 0; j < 8; ++j) {
    ushort h = f2bf(v[j]);
    hi[j] = h;
    lo[j] = f2bf(v[j] - bf2f(h));
  }
  *(ushort8*)&xh[p * 768 + seg * 8] = hi;
  *(ushort8*)&xl[p * 768 + seg * 8] = lo;
}

// ============ G1: QKV of the 4 global tokens (4 x 2304), fp32 ============
__global__ void k_gqkv(const float* __restrict__ gtok,
                       const float* __restrict__ w_qkv,
                       float* __restrict__ qkv_g) {
  int idx = blockIdx.x * 256 + threadIdx.x;   // 0..9215
  int tok = idx / 2304, c = idx - tok * 2304;
  const float* gp = gtok + tok * 768;
  float s = 0.f;
  for (int d = 0; d < 768; ++d) s += gp[d] * w_qkv[d * 2304 + c];
  qkv_g[idx] = s;
}

// ============ F: fused QKV-GEMM (256x192 tile, pipelined) + attention ============
// grid = 1536. XCD-local decode: xcd=bid&7, k=bid>>3, h=k%12, mblk=(k/12)*8+xcd
// so the 12 head-blocks sharing one A-tile are consecutive on ONE XCD (L2 reuse).
__global__ __launch_bounds__(512, 2) void k_fused(
    const ushort* __restrict__ xh, const ushort* __restrict__ xl,
    const ushort* __restrict__ Whi, const ushort* __restrict__ Wlo,
    const float* __restrict__ qnw, const float* __restrict__ knw,
    const float* __restrict__ qkv_g, float* __restrict__ part,
    ushort* __restrict__ o_hi, ushort* __restrict__ o_lo) {
  __shared__ __align__(16) char smem[114688];   // 2 x (A 32KB + B 24KB)
  const int tid = threadIdx.x;
  const int lane = tid & 63;
  const int wv = tid >> 6;
  const int wm = wv >> 1, wn = wv & 1;          // 4M x 2N
  const int l15 = lane & 15, kq = lane >> 4, ln7 = lane & 7;
  const int bid = blockIdx.x;
  const int xcd = bid & 7, kk_ = bid >> 3;
  const int h = kk_ % 12;
  const int mblk = (kk_ / 12) * 8 + xcd;
  const int r0 = mblk * 256;
  const int cb0 = h * 192;

  int gA[4], lA[4], gB[3], lB[3];
#pragma unroll
  for (int j = 0; j < 4; ++j) {
    int c = j * 512 + tid; int row = c >> 3, sl = c & 7;
    gA[j] = (r0 + row) * 768 + ((sl ^ (row & 7)) << 3); lA[j] = c << 4;
  }
#pragma unroll
  for (int j = 0; j < 3; ++j) {
    int c = j * 512 + tid; int row = c >> 3, sl = c & 7;
    gB[j] = (cb0 + row) * 768 + ((sl ^ (row & 7)) << 3); lB[j] = 32768 + (c << 4);
  }

  f32x4 acc[4][6];
#pragma unroll
  for (int i = 0; i < 4; ++i)
#pragma unroll
    for (int j = 0; j < 6; ++j) acc[i][j] = (f32x4){0.f, 0.f, 0.f, 0.f};

  auto STAGE = [&](int t, int bufi) {
    const ushort* Ap = (t < 24) ? xh : xl;
    const ushort* Bp = (t >= 12 && t < 24) ? Wlo : Whi;
    int seg = (t >= 24) ? (t - 24) : (t >= 12) ? (t - 12) : t;
    int kk = seg << 6;
    char* bb = smem + bufi * 57344;
#pragma unroll
    for (int j = 0; j < 4; ++j) gl_lds16(Ap + gA[j] + kk, bb + lA[j]);
#pragma unroll
    for (int j = 0; j < 3; ++j) gl_lds16(Bp + gB[j] + kk, bb + lB[j]);
  };

  auto COMPUTE = [&](int bufi) {
    const char* ba = smem + bufi * 57344;
    const char* bbp = ba + 32768;
#pragma unroll
    for (int ks = 0; ks < 2; ++ks) {
      const int so = (((ks << 2) | kq) ^ ln7) << 4;
      short8 a[4], b[6];
#pragma unroll
      for (int mf = 0; mf < 4; ++mf)
        a[mf] = *(const short8*)(ba + (wm * 64 + mf * 16 + l15) * 128 + so);
#pragma unroll
      for (int nf = 0; nf < 6; ++nf)
        b[nf] = *(const short8*)(bbp + (wn * 96 + nf * 16 + l15) * 128 + so);
#pragma unroll
      for (int mf = 0; mf < 4; ++mf)
#pragma unroll
        for (int nf = 0; nf < 6; ++nf)
          acc[mf][nf] = __builtin_amdgcn_mfma_f32_16x16x32_bf16(a[mf], b[nf], acc[mf][nf], 0, 0, 0);
    }
  };

  STAGE(0, 0); STAGE(1, 1);
  WAITV(7); BAR();
  for (int t = 0; t < 36; ++t) {
    int cur = t & 1;
    COMPUTE(cur);
    BAR();
    if (t < 34) { STAGE(t + 2, cur); WAITV(7); }
    else { WAITV(0); }
    BAR();
  }

  // ======== attention: 2 passes x 2 windows; per-window 256-thread groups ========
  const int g = tid >> 8, tl = tid & 255;
  for (int pass = 0; pass < 2; ++pass) {
    // scatter this pass's windows (waves with wm in {2p, 2p+1}) to LDS
    if ((wm >> 1) == pass) {
      char* wb = smem + (wm & 1) * 52480;
#pragma unroll
      for (int mf = 0; mf < 4; ++mf) {
        int tok = mf * 16 + kq * 4;
#pragma unroll
        for (int nf = 0; nf < 6; ++nf) {
          int col = wn * 96 + nf * 16 + l15;
          int pp = col >> 6, d = col & 63;
          float* dst = (float*)(wb + pp * 17152);
#pragma unroll
          for (int e = 0; e < 4; ++e) dst[(tok + e) * 67 + d] = acc[mf][nf][e];
        }
      }
    }
    __syncthreads();

    float* qs = (float*)(smem + g * 52480);
    float* ks = qs + 4288;
    float* vs = qs + 8576;
    float* ps_c = qs + 12864;
    float* sps = qs;
    const int widx = mblk * 4 + pass * 2 + g;
    const int b = widx >> 6, wl = widx & 63;

    // ---- phase C: global-attn partials (raw k,v) ----
    {
      int qi = tl >> 6, j = tl & 63;
      const float* qgp = qkv_g + qi * 2304 + h * 64;
      float s = 0.f;
      for (int d = 0; d < 64; ++d) s += qgp[d] * ks[j * 67 + d];
      s *= SCALE;
      float m = s;
#pragma unroll
      for (int o = 1; o < 64; o <<= 1) m = fmaxf(m, __shfl_xor(m, o));
      float p = expf(s - m);
      float l = p;
#pragma unroll
      for (int o = 1; o < 64; o <<= 1) l += __shfl_xor(l, o);
      ps_c[qi * 64 + j] = p;
      int pbase = ((b * 12 + h) * 64 + wl) * 272;
      if (j == 0) { part[pbase + 256 + qi] = m; part[pbase + 260 + qi] = l; }
      __syncthreads();
      float a = 0.f;
      for (int jj = 0; jj < 64; ++jj) a += ps_c[qi * 64 + jj] * vs[jj * 67 + j];
      part[pbase + qi * 64 + j] = a;
    }

    // ---- rmsnorm(q), rmsnorm(k) ----
    __syncthreads();
    if (tl < 128) {
      int which = tl >> 6, tk = tl & 63;
      float* row = which ? (ks + tk * 67) : (qs + tk * 67);
      const float* nw = which ? knw : qnw;
      float ss = 0.f;
      for (int d = 0; d < 64; ++d) { float v0 = row[d]; ss += v0 * v0; }
      float sc = 1.0f / sqrtf(ss * 0.015625f + EPS_RMS);
      for (int d = 0; d < 64; ++d) row[d] = row[d] * sc * nw[d];
    }
    __syncthreads();

    // ---- phase B: local attention ----
    {
      int i = tl >> 2, g16 = tl & 3;
      float sv[16];
#pragma unroll
      for (int jj = 0; jj < 16; ++jj) sv[jj] = 0.f;
      for (int d = 0; d < 64; ++d) {
        float qa = qs[i * 67 + d];
#pragma unroll
        for (int jj = 0; jj < 16; ++jj) sv[jj] += qa * ks[(g16 * 16 + jj) * 67 + d];
      }
      float m = -1e30f;
#pragma unroll
      for (int jj = 0; jj < 16; ++jj) { sv[jj] *= SCALE; m = fmaxf(m, sv[jj]); }
      m = fmaxf(m, __shfl_xor(m, 1));
      m = fmaxf(m, __shfl_xor(m, 2));
      float l = 0.f;
#pragma unroll
      for (int jj = 0; jj < 16; ++jj) { sv[jj] = expf(sv[jj] - m); l += sv[jj]; }
      l += __shfl_xor(l, 1);
      l += __shfl_xor(l, 2);
      __syncthreads();          // all reads of qs done before sps overwrite
#pragma unroll
      for (int jj = 0; jj < 16; ++jj) sps[i * 67 + g16 * 16 + jj] = sv[jj];
      __syncthreads();
      float oa[16];
#pragma unroll
      for (int dd = 0; dd < 16; ++dd) oa[dd] = 0.f;
      for (int j = 0; j < 64; ++j) {
        float pv = sps[i * 67 + j];
#pragma unroll
        for (int dd = 0; dd < 16; ++dd) oa[dd] += pv * vs[j * 67 + g16 * 16 + dd];
      }
      float invl = 1.0f / l;
      int orow = (widx * 64 + i) * 768 + h * 64 + g16 * 16;
      ushort hi[16], lo[16];
#pragma unroll
      for (int dd = 0; dd < 16; ++dd) {
        float vv = oa[dd] * invl;
        hi[dd] = f2bf(vv);
        lo[dd] = f2bf(vv - bf2f(hi[dd]));
      }
      ushort8 h0, h1, l0, l1;
#pragma unroll
      for (int dd = 0; dd < 8; ++dd) {
        h0[dd] = hi[dd]; h1[dd] = hi[dd + 8];
        l0[dd] = lo[dd]; l1[dd] = lo[dd + 8];
      }
      *(ushort8*)&o_hi[orow] = h0;
      *(ushort8*)&o_hi[orow + 8] = h1;
      *(ushort8*)&o_lo[orow] = l0;
      *(ushort8*)&o_lo[orow + 8] = l1;
    }
    __syncthreads();
  }
}

// ============ P: projection out = o @ w_out + g_term (256x192 tile, pipelined) ====
// grid = 512. XCD-local decode: 4 col-blocks sharing an A-tile consecutive per XCD.
__global__ __launch_bounds__(512, 2) void k_proj8(
    const ushort* __restrict__ o_hi, const ushort* __restrict__ o_lo,
    const ushort* __restrict__ Whi, const ushort* __restrict__ Wlo,
    const float* __restrict__ g_term, float* __restrict__ out) {
  __shared__ __align__(16) char smem[114688];
  const int tid = threadIdx.x;
  const int lane = tid & 63;
  const int wv = tid >> 6;
  const int wm = wv >> 1, wn = wv & 1;
  const int l15 = lane & 15, kq = lane >> 4, ln7 = lane & 7;
  const int bid = blockIdx.x;
  const int xcd = bid & 7, kk_ = bid >> 3;
  const int cblk = kk_ % 4;
  const int mblk = (kk_ / 4) * 8 + xcd;
  const int r0 = mblk * 256;
  const int cb0 = cblk * 192;

  int gA[4], lA[4], gB[3], lB[3];
#pragma unroll
  for (int j = 0; j < 4; ++j) {
    int c = j * 512 + tid; int row = c >> 3, sl = c & 7;
    gA[j] = (r0 + row) * 768 + ((sl ^ (row & 7)) << 3); lA[j] = c << 4;
  }
#pragma unroll
  for (int j = 0; j < 3; ++j) {
    int c = j * 512 + tid; int row = c >> 3, sl = c & 7;
    gB[j] = (cb0 + row) * 768 + ((sl ^ (row & 7)) << 3); lB[j] = 32768 + (c << 4);
  }

  f32x4 acc[4][6];
#pragma unroll
  for (int i = 0; i < 4; ++i)
#pragma unroll
    for (int j = 0; j < 6; ++j) acc[i][j] = (f32x4){0.f, 0.f, 0.f, 0.f};

  auto STAGE = [&](int t, int bufi) {
    const ushort* Ap = (t < 24) ? o_hi : o_lo;
    const ushort* Bp = (t >= 12 && t < 24) ? Wlo : Whi;
    int seg = (t >= 24) ? (t - 24) : (t >= 12) ? (t - 12) : t;
    int kk = seg << 6;
    char* bb = smem + bufi * 57344;
#pragma unroll
    for (int j = 0; j < 4; ++j) gl_lds16(Ap + gA[j] + kk, bb + lA[j]);
#pragma unroll
    for (int j = 0; j < 3; ++j) gl_lds16(Bp + gB[j] + kk, bb + lB[j]);
  };

  auto COMPUTE = [&](int bufi) {
    const char* ba = smem + bufi * 57344;
    const char* bbp = ba + 32768;
#pragma unroll
    for (int ks = 0; ks < 2; ++ks) {
      const int so = (((ks << 2) | kq) ^ ln7) << 4;
      short8 a[4], b[6];
#pragma unroll
      for (int mf = 0; mf < 4; ++mf)
        a[mf] = *(const short8*)(ba + (wm * 64 + mf * 16 + l15) * 128 + so);
#pragma unroll
      for (int nf = 0; nf < 6; ++nf)
        b[nf] = *(const short8*)(bbp + (wn * 96 + nf * 16 + l15) * 128 + so);
#pragma unroll
      for (int mf = 0; mf < 4; ++mf)
#pragma unroll
        for (int nf = 0; nf < 6; ++nf)
          acc[mf][nf] = __builtin_amdgcn_mfma_f32_16x16x32_bf16(a[mf], b[nf], acc[mf][nf], 0, 0, 0);
    }
  };

  STAGE(0, 0); STAGE(1, 1);
  WAITV(7); BAR();
  for (int t = 0; t < 36; ++t) {
    int cur = t & 1;
    COMPUTE(cur);
    BAR();
    if (t < 34) { STAGE(t + 2, cur); WAITV(7); }
    else { WAITV(0); }
    BAR();
  }

#pragma unroll
  for (int mf = 0; mf < 4; ++mf) {
    int prow0 = r0 + wm * 64 + mf * 16 + kq * 4;
#pragma unroll
    for (int nf = 0; nf < 6; ++nf) {
      int col = cb0 + wn * 96 + nf * 16 + l15;
#pragma unroll
      for (int e = 0; e < 4; ++e) {
        int p = prow0 + e;
        out[nat_row(p) * 768 + col] = acc[mf][nf][e] + g_term[(p >> 12) * 768 + col];
      }
    }
  }
}

// ============ G3: combine global-attn partials -> og_mean (B x 768) ============
__global__ void k_greduce(const float* __restrict__ qkv_g,
                          const float* __restrict__ part,
                          float* __restrict__ og_mean) {
  __shared__ float red[4][64];
  int bh = blockIdx.x;
  int b = bh / 12, h = bh - b * 12;
  int tid = threadIdx.x;
  int qi = tid >> 6, d = tid & 63;
  float M = -1e30f, L = 0.f, A = 0.f;
  float qd = qkv_g[qi * 2304 + h * 64 + d];
#pragma unroll
  for (int gk = 0; gk < 4; ++gk) {
    float kd = qkv_g[gk * 2304 + 768 + h * 64 + d];
    float prod = qd * kd;
#pragma unroll
    for (int o = 1; o < 64; o <<= 1) prod += __shfl_xor(prod, o);
    float s = prod * SCALE;
    float Mn = fmaxf(M, s);
    float f = expf(M - Mn), e = expf(s - Mn);
    float vd = qkv_g[gk * 2304 + 1536 + h * 64 + d];
    A = A * f + e * vd;
    L = L * f + e;
    M = Mn;
  }
  for (int p = 0; p < 64; ++p) {
    int pbase = ((b * 12 + h) * 64 + p) * 272;
    float mp = part[pbase + 256 + qi];
    float lp = part[pbase + 260 + qi];
    float ap = part[pbase + qi * 64 + d];
    float Mn = fmaxf(M, mp);
    float f = expf(M - Mn), e = expf(mp - Mn);
    A = A * f + ap * e;
    L = L * f + lp * e;
    M = Mn;
  }
  red[qi][d] = A / L;
  __syncthreads();
  if (tid < 64) {
    float s = (red[0][d] + red[1][d] + red[2][d] + red[3][d]) * 0.25f;
    og_mean[b * 768 + h * 64 + d] = s;
  }
}

// ============ G4: g_term = og_mean @ w_out (B x 768), fp32 ============
__global__ void k_gterm(const float* __restrict__ og_mean,
                        const float* __restrict__ w_out,
                        float* __restrict__ g_term) {
  int idx = blockIdx.x * 256 + threadIdx.x;   // 0..6143
  int b = idx / 768, c = idx - b * 768;
  const float* op = og_mean + b * 768;
  float s = 0.f;
  for (int d = 0; d < 768; ++d) s += op[d] * w_out[d * 768 + c];
  g_term[idx] = s;
}

extern "C" void kernel_launch(void* const* d_in, const int* in_sizes, int n_in,
                              void* d_out, int out_size, void* d_ws, size_t ws_size,
                              hipStream_t stream) {
  const float* x      = (const float*)d_in[0];
  const float* w_qkv  = (const float*)d_in[1];
  const float* w_out  = (const float*)d_in[2];
  const float* qnw    = (const float*)d_in[3];
  const float* knw    = (const float*)d_in[4];
  const float* gtok   = (const float*)d_in[5];
  float* out = (float*)d_out;

  // ---- ws layout (~117 MB) ----
  ushort* WhiQ = (ushort*)d_ws;                 // 2304*768
  ushort* WloQ = WhiQ + 2304 * 768;
  ushort* WhiO = WloQ + 2304 * 768;             // 768*768
  ushort* WloO = WhiO + 768 * 768;
  ushort* o_hi = WloO + 768 * 768;              // 32768*768
  ushort* o_lo = o_hi + 32768 * 768;
  float* qkv_g   = (float*)(o_lo + 32768 * 768);
  float* part    = qkv_g + 9216;                // 8*12*64*272
  float* og_mean = part + 8 * 12 * 64 * 272;
  float* g_term  = og_mean + 6144;

  // x hi/lo planes live in d_out until the final projection overwrites it
  ushort* xh = (ushort*)d_out;                  // 32768*768
  ushort* xl = xh + 32768 * 768;

  k_prep  <<<dim3(36, 12), 256, 0, stream>>>(w_qkv, 2304, 0, WhiQ, WloQ);
  k_prep  <<<dim3(12, 12), 256, 0, stream>>>(w_out,  768, 1, WhiO, WloO);
  k_gqkv  <<<36,    256, 0, stream>>>(gtok, w_qkv, qkv_g);
  k_xsplit<<<12288, 256, 0, stream>>>(x, xh, xl);

  k_fused <<<1536, 512, 0, stream>>>(xh, xl, WhiQ, WloQ, qnw, knw, qkv_g, part, o_hi, o_lo);

  k_greduce<<<96, 256, 0, stream>>>(qkv_g, part, og_mean);
  k_gterm  <<<24, 256, 0, stream>>>(og_mean, w_out, g_term);
  k_proj8 <<<512, 512, 0, stream>>>(o_hi, o_lo, WhiO, WloO, g_term, out);
}

// Round 7
// 825.443 us; speedup vs baseline: 3.1567x; 1.0723x over previous
//
#include <hip/hip_runtime.h>
#include <hip/hip_bf16.h>

typedef short short8 __attribute__((ext_vector_type(8)));
typedef unsigned short ushort8 __attribute__((ext_vector_type(8)));
typedef float f32x4 __attribute__((ext_vector_type(4)));
typedef unsigned short ushort;

constexpr float SCALE = 0.125f;   // 64^-0.5
constexpr float EPS_RMS = 1e-6f;

#define BAR() asm volatile("s_barrier" ::: "memory")
#define WAITV(N) asm volatile("s_waitcnt vmcnt(" #N ")" ::: "memory")

__device__ __forceinline__ ushort f2bf(float f) {
  return __builtin_bit_cast(unsigned short, __float2bfloat16(f));
}
__device__ __forceinline__ float bf2f(ushort u) {
  return __bfloat162float(__builtin_bit_cast(__hip_bfloat16, u));
}
__device__ __forceinline__ void gl_lds16(const void* g, void* l) {
  __builtin_amdgcn_global_load_lds((const __attribute__((address_space(1))) void*)g,
                                   (__attribute__((address_space(3))) void*)l, 16, 0, 0);
}

// permuted row p -> natural token row
__device__ __forceinline__ int nat_row(int p) {
  return (p & ~4095) | (((p >> 9) & 7) << 9) | (((p >> 3) & 7) << 6) |
         (((p >> 6) & 7) << 3) | (p & 7);
}

// ============ P0: transpose + split weights into bf16 hi/lo planes ============
__global__ void k_prep(const float* __restrict__ src, int src_ld, int mode,
                       ushort* __restrict__ hi, ushort* __restrict__ lo) {
  __shared__ float tile[64][65];
  int rb = blockIdx.x, db = blockIdx.y;
  int tid = threadIdx.x;
#pragma unroll
  for (int e = 0; e < 16; ++e) {
    int idx = e * 256 + tid;
    int dd = idx >> 6, cc = idx & 63;
    int sc;
    if (mode == 0) { int h = rb / 3, p = rb % 3; sc = p * 768 + h * 64 + cc; }
    else sc = rb * 64 + cc;
    tile[dd][cc] = src[(db * 64 + dd) * src_ld + sc];
  }
  __syncthreads();
#pragma unroll
  for (int e = 0; e < 16; ++e) {
    int idx = e * 256 + tid;
    int cc = idx >> 6, dd = idx & 63;
    float f = tile[dd][cc];
    ushort h = f2bf(f);
    ushort l = f2bf(f - bf2f(h));
    int o = (rb * 64 + cc) * 768 + db * 64 + dd;
    hi[o] = h;
    lo[o] = l;
  }
}

// ============ X: split x into bf16 hi/lo planes, window-permuted rows ============
__global__ void k_xsplit(const float* __restrict__ x,
                         ushort* __restrict__ xh, ushort* __restrict__ xl) {
  int idx = blockIdx.x * 256 + threadIdx.x;   // 32768*96
  int p = idx / 96, seg = idx - p * 96;
  int n = nat_row(p);
  const float* src = x + n * 768 + seg * 8;
  float4 a = *(const float4*)src;
  float4 c = *(const float4*)(src + 4);
  float v[8] = {a.x, a.y, a.z, a.w, c.x, c.y, c.z, c.w};
  ushort8 hi, lo;
#pragma unroll
  for (int j = 0; j < 8; ++j) {
    ushort h = f2bf(v[j]);
    hi[j] = h;
    lo[j] = f2bf(v[j] - bf2f(h));
  }
  *(ushort8*)&xh[p * 768 + seg * 8] = hi;
  *(ushort8*)&xl[p * 768 + seg * 8] = lo;
}

// ============ G1: QKV of the 4 global tokens (4 x 2304), fp32 ============
__global__ void k_gqkv(const float* __restrict__ gtok,
                       const float* __restrict__ w_qkv,
                       float* __restrict__ qkv_g) {
  int idx = blockIdx.x * 256 + threadIdx.x;   // 0..9215
  int tok = idx / 2304, c = idx - tok * 2304;
  const float* gp = gtok + tok * 768;
  float s = 0.f;
  for (int d = 0; d < 768; ++d) s += gp[d] * w_qkv[d * 2304 + c];
  qkv_g[idx] = s;
}

// ============ F: fused QKV-GEMM (256x192, 4-plane BK=32) + attention ============
// grid = 1536, XCD-local decode. Buffer: [Ah 16K][Al 16K][Bh 12K][Bl 12K] = 56KB x2.
// Per K=32 slice: read ah/al/bh/bl frags once, fire 72 MFMA (3-term split).
__global__ __launch_bounds__(512, 2) void k_fused(
    const ushort* __restrict__ xh, const ushort* __restrict__ xl,
    const ushort* __restrict__ Whi, const ushort* __restrict__ Wlo,
    const float* __restrict__ qnw, const float* __restrict__ knw,
    const float* __restrict__ qkv_g, float* __restrict__ part,
    ushort* __restrict__ o_hi, ushort* __restrict__ o_lo) {
  __shared__ __align__(16) char smem[114688];   // 2 x 56KB
  const int tid = threadIdx.x;
  const int lane = tid & 63;
  const int wv = tid >> 6;
  const int wm = wv >> 1, wn = wv & 1;          // 4M x 2N, wave tile 64x96
  const int l15 = lane & 15, kq = lane >> 4;
  const int bid = blockIdx.x;
  const int xcd = bid & 7, kk_ = bid >> 3;
  const int h = kk_ % 12;
  const int mblk = (kk_ / 12) * 8 + xcd;
  const int r0 = mblk * 256;
  const int cb0 = h * 192;

  // staging maps: A region 32KB (Ah|Al), B region 24KB (Bh|Bl), 16B per thread-load
  int gAo[4], lA[4]; bool pA[4];
#pragma unroll
  for (int j = 0; j < 4; ++j) {
    int byo = (j * 512 + tid) * 16;
    pA[j] = byo >= 16384;
    int wb = byo & 16383;
    int row = wb >> 6, sl = (wb >> 4) & 3;
    int kb = sl ^ ((row >> 1) & 3);
    gAo[j] = (r0 + row) * 768 + kb * 8;
    lA[j] = byo;
  }
  int gBo[3], lB[3]; bool pB[3];
#pragma unroll
  for (int j = 0; j < 3; ++j) {
    int byo = (j * 512 + tid) * 16;
    pB[j] = byo >= 12288;
    int wb = pB[j] ? byo - 12288 : byo;
    int row = wb >> 6, sl = (wb >> 4) & 3;
    int kb = sl ^ ((row >> 1) & 3);
    gBo[j] = (cb0 + row) * 768 + kb * 8;
    lB[j] = 32768 + byo;
  }

  f32x4 acc[4][6];
#pragma unroll
  for (int i = 0; i < 4; ++i)
#pragma unroll
    for (int j = 0; j < 6; ++j) acc[i][j] = (f32x4){0.f, 0.f, 0.f, 0.f};

  auto STAGE = [&](int t, int bufi) {
    const int kk = t * 32;
    char* bb = smem + bufi * 57344;
#pragma unroll
    for (int j = 0; j < 4; ++j) {
      const ushort* Ap = pA[j] ? xl : xh;
      gl_lds16(Ap + gAo[j] + kk, bb + lA[j]);
    }
#pragma unroll
    for (int j = 0; j < 3; ++j) {
      const ushort* Bp = pB[j] ? Wlo : Whi;
      gl_lds16(Bp + gBo[j] + kk, bb + lB[j]);
    }
  };

  auto COMPUTE = [&](int bufi) {
    const char* ba = smem + bufi * 57344;
    short8 ah[4], al[4], bh[6], bl[6];
#pragma unroll
    for (int mf = 0; mf < 4; ++mf) {
      int row = wm * 64 + mf * 16 + l15;
      int so = (kq ^ ((row >> 1) & 3)) << 4;
      ah[mf] = *(const short8*)(ba + row * 64 + so);
      al[mf] = *(const short8*)(ba + 16384 + row * 64 + so);
    }
#pragma unroll
    for (int nf = 0; nf < 6; ++nf) {
      int row = wn * 96 + nf * 16 + l15;
      int so = (kq ^ ((row >> 1) & 3)) << 4;
      bh[nf] = *(const short8*)(ba + 32768 + row * 64 + so);
      bl[nf] = *(const short8*)(ba + 45056 + row * 64 + so);
    }
#pragma unroll
    for (int mf = 0; mf < 4; ++mf)
#pragma unroll
      for (int nf = 0; nf < 6; ++nf) {
        acc[mf][nf] = __builtin_amdgcn_mfma_f32_16x16x32_bf16(ah[mf], bh[nf], acc[mf][nf], 0, 0, 0);
        acc[mf][nf] = __builtin_amdgcn_mfma_f32_16x16x32_bf16(ah[mf], bl[nf], acc[mf][nf], 0, 0, 0);
        acc[mf][nf] = __builtin_amdgcn_mfma_f32_16x16x32_bf16(al[mf], bh[nf], acc[mf][nf], 0, 0, 0);
      }
  };

  STAGE(0, 0); STAGE(1, 1);
  WAITV(7); BAR();
  for (int t = 0; t < 24; ++t) {
    int cur = t & 1;
    COMPUTE(cur);
    BAR();
    if (t < 22) { STAGE(t + 2, cur); WAITV(7); }
    else { WAITV(0); }
    BAR();
  }

  // ======== attention: 2 passes x 2 windows; per-window 256-thread groups ========
  const int g = tid >> 8, tl = tid & 255;
  for (int pass = 0; pass < 2; ++pass) {
    // scatter this pass's windows (waves with wm in {2p, 2p+1}) to LDS
    if ((wm >> 1) == pass) {
      char* wb = smem + (wm & 1) * 52480;
#pragma unroll
      for (int mf = 0; mf < 4; ++mf) {
        int tok = mf * 16 + kq * 4;
#pragma unroll
        for (int nf = 0; nf < 6; ++nf) {
          int col = wn * 96 + nf * 16 + l15;
          int pp = col >> 6, d = col & 63;
          float* dst = (float*)(wb + pp * 17152);
#pragma unroll
          for (int e = 0; e < 4; ++e) dst[(tok + e) * 67 + d] = acc[mf][nf][e];
        }
      }
    }
    __syncthreads();

    float* qs = (float*)(smem + g * 52480);
    float* ks = qs + 4288;
    float* vs = qs + 8576;
    float* ps_c = qs + 12864;
    float* sps = qs;
    const int widx = mblk * 4 + pass * 2 + g;
    const int b = widx >> 6, wl = widx & 63;

    // ---- phase C: global-attn partials (raw k,v) ----
    {
      int qi = tl >> 6, j = tl & 63;
      const float* qgp = qkv_g + qi * 2304 + h * 64;
      float s = 0.f;
      for (int d = 0; d < 64; ++d) s += qgp[d] * ks[j * 67 + d];
      s *= SCALE;
      float m = s;
#pragma unroll
      for (int o = 1; o < 64; o <<= 1) m = fmaxf(m, __shfl_xor(m, o));
      float p = expf(s - m);
      float l = p;
#pragma unroll
      for (int o = 1; o < 64; o <<= 1) l += __shfl_xor(l, o);
      ps_c[qi * 64 + j] = p;
      int pbase = ((b * 12 + h) * 64 + wl) * 272;
      if (j == 0) { part[pbase + 256 + qi] = m; part[pbase + 260 + qi] = l; }
      __syncthreads();
      float a = 0.f;
      for (int jj = 0; jj < 64; ++jj) a += ps_c[qi * 64 + jj] * vs[jj * 67 + j];
      part[pbase + qi * 64 + j] = a;
    }

    // ---- rmsnorm(q), rmsnorm(k) ----
    __syncthreads();
    if (tl < 128) {
      int which = tl >> 6, tk = tl & 63;
      float* row = which ? (ks + tk * 67) : (qs + tk * 67);
      const float* nw = which ? knw : qnw;
      float ss = 0.f;
      for (int d = 0; d < 64; ++d) { float v0 = row[d]; ss += v0 * v0; }
      float sc = 1.0f / sqrtf(ss * 0.015625f + EPS_RMS);
      for (int d = 0; d < 64; ++d) row[d] = row[d] * sc * nw[d];
    }
    __syncthreads();

    // ---- phase B: local attention ----
    {
      int i = tl >> 2, g16 = tl & 3;
      float sv[16];
#pragma unroll
      for (int jj = 0; jj < 16; ++jj) sv[jj] = 0.f;
      // interleaved row map (g16 + 4*jj): the 4 lanes of a quad read 4 ADJACENT
      // rows -> distinct banks (conflict-free); sps layout itself is unchanged.
      for (int d = 0; d < 64; ++d) {
        float qa = qs[i * 67 + d];
#pragma unroll
        for (int jj = 0; jj < 16; ++jj) sv[jj] += qa * ks[(g16 + 4 * jj) * 67 + d];
      }
      float m = -1e30f;
#pragma unroll
      for (int jj = 0; jj < 16; ++jj) { sv[jj] *= SCALE; m = fmaxf(m, sv[jj]); }
      m = fmaxf(m, __shfl_xor(m, 1));
      m = fmaxf(m, __shfl_xor(m, 2));
      float l = 0.f;
#pragma unroll
      for (int jj = 0; jj < 16; ++jj) { sv[jj] = expf(sv[jj] - m); l += sv[jj]; }
      l += __shfl_xor(l, 1);
      l += __shfl_xor(l, 2);
      __syncthreads();          // all reads of qs done before sps overwrite
#pragma unroll
      for (int jj = 0; jj < 16; ++jj) sps[i * 67 + g16 + 4 * jj] = sv[jj];
      __syncthreads();
      float oa[16];
#pragma unroll
      for (int dd = 0; dd < 16; ++dd) oa[dd] = 0.f;
      for (int j = 0; j < 64; ++j) {
        float pv = sps[i * 67 + j];
#pragma unroll
        for (int dd = 0; dd < 16; ++dd) oa[dd] += pv * vs[j * 67 + g16 * 16 + dd];
      }
      float invl = 1.0f / l;
      int orow = (widx * 64 + i) * 768 + h * 64 + g16 * 16;
      ushort hi[16], lo[16];
#pragma unroll
      for (int dd = 0; dd < 16; ++dd) {
        float vv = oa[dd] * invl;
        hi[dd] = f2bf(vv);
        lo[dd] = f2bf(vv - bf2f(hi[dd]));
      }
      ushort8 h0, h1, l0, l1;
#pragma unroll
      for (int dd = 0; dd < 8; ++dd) {
        h0[dd] = hi[dd]; h1[dd] = hi[dd + 8];
        l0[dd] = lo[dd]; l1[dd] = lo[dd + 8];
      }
      *(ushort8*)&o_hi[orow] = h0;
      *(ushort8*)&o_hi[orow + 8] = h1;
      *(ushort8*)&o_lo[orow] = l0;
      *(ushort8*)&o_lo[orow + 8] = l1;
    }
    __syncthreads();
  }
}

// ============ P: projection out = o @ w_out + g_term (4-plane BK=32) ============
// grid = 512, XCD-local decode.
__global__ __launch_bounds__(512, 2) void k_proj8(
    const ushort* __restrict__ o_hi, const ushort* __restrict__ o_lo,
    const ushort* __restrict__ Whi, const ushort* __restrict__ Wlo,
    const float* __restrict__ g_term, float* __restrict__ out) {
  __shared__ __align__(16) char smem[114688];
  const int tid = threadIdx.x;
  const int lane = tid & 63;
  const int wv = tid >> 6;
  const int wm = wv >> 1, wn = wv & 1;
  const int l15 = lane & 15, kq = lane >> 4;
  const int bid = blockIdx.x;
  const int xcd = bid & 7, kk_ = bid >> 3;
  const int cblk = kk_ % 4;
  const int mblk = (kk_ / 4) * 8 + xcd;
  const int r0 = mblk * 256;
  const int cb0 = cblk * 192;

  int gAo[4], lA[4]; bool pA[4];
#pragma unroll
  for (int j = 0; j < 4; ++j) {
    int byo = (j * 512 + tid) * 16;
    pA[j] = byo >= 16384;
    int wb = byo & 16383;
    int row = wb >> 6, sl = (wb >> 4) & 3;
    int kb = sl ^ ((row >> 1) & 3);
    gAo[j] = (r0 + row) * 768 + kb * 8;
    lA[j] = byo;
  }
  int gBo[3], lB[3]; bool pB[3];
#pragma unroll
  for (int j = 0; j < 3; ++j) {
    int byo = (j * 512 + tid) * 16;
    pB[j] = byo >= 12288;
    int wb = pB[j] ? byo - 12288 : byo;
    int row = wb >> 6, sl = (wb >> 4) & 3;
    int kb = sl ^ ((row >> 1) & 3);
    gBo[j] = (cb0 + row) * 768 + kb * 8;
    lB[j] = 32768 + byo;
  }

  f32x4 acc[4][6];
#pragma unroll
  for (int i = 0; i < 4; ++i)
#pragma unroll
    for (int j = 0; j < 6; ++j) acc[i][j] = (f32x4){0.f, 0.f, 0.f, 0.f};

  auto STAGE = [&](int t, int bufi) {
    const int kk = t * 32;
    char* bb = smem + bufi * 57344;
#pragma unroll
    for (int j = 0; j < 4; ++j) {
      const ushort* Ap = pA[j] ? o_lo : o_hi;
      gl_lds16(Ap + gAo[j] + kk, bb + lA[j]);
    }
#pragma unroll
    for (int j = 0; j < 3; ++j) {
      const ushort* Bp = pB[j] ? Wlo : Whi;
      gl_lds16(Bp + gBo[j] + kk, bb + lB[j]);
    }
  };

  auto COMPUTE = [&](int bufi) {
    const char* ba = smem + bufi * 57344;
    short8 ah[4], al[4], bh[6], bl[6];
#pragma unroll
    for (int mf = 0; mf < 4; ++mf) {
      int row = wm * 64 + mf * 16 + l15;
      int so = (kq ^ ((row >> 1) & 3)) << 4;
      ah[mf] = *(const short8*)(ba + row * 64 + so);
      al[mf] = *(const short8*)(ba + 16384 + row * 64 + so);
    }
#pragma unroll
    for (int nf = 0; nf < 6; ++nf) {
      int row = wn * 96 + nf * 16 + l15;
      int so = (kq ^ ((row >> 1) & 3)) << 4;
      bh[nf] = *(const short8*)(ba + 32768 + row * 64 + so);
      bl[nf] = *(const short8*)(ba + 45056 + row * 64 + so);
    }
#pragma unroll
    for (int mf = 0; mf < 4; ++mf)
#pragma unroll
      for (int nf = 0; nf < 6; ++nf) {
        acc[mf][nf] = __builtin_amdgcn_mfma_f32_16x16x32_bf16(ah[mf], bh[nf], acc[mf][nf], 0, 0, 0);
        acc[mf][nf] = __builtin_amdgcn_mfma_f32_16x16x32_bf16(ah[mf], bl[nf], acc[mf][nf], 0, 0, 0);
        acc[mf][nf] = __builtin_amdgcn_mfma_f32_16x16x32_bf16(al[mf], bh[nf], acc[mf][nf], 0, 0, 0);
      }
  };

  STAGE(0, 0); STAGE(1, 1);
  WAITV(7); BAR();
  for (int t = 0; t < 24; ++t) {
    int cur = t & 1;
    COMPUTE(cur);
    BAR();
    if (t < 22) { STAGE(t + 2, cur); WAITV(7); }
    else { WAITV(0); }
    BAR();
  }

#pragma unroll
  for (int mf = 0; mf < 4; ++mf) {
    int prow0 = r0 + wm * 64 + mf * 16 + kq * 4;
#pragma unroll
    for (int nf = 0; nf < 6; ++nf) {
      int col = cb0 + wn * 96 + nf * 16 + l15;
#pragma unroll
      for (int e = 0; e < 4; ++e) {
        int p = prow0 + e;
        out[nat_row(p) * 768 + col] = acc[mf][nf][e] + g_term[(p >> 12) * 768 + col];
      }
    }
  }
}

// ============ G3: combine global-attn partials -> og_mean (B x 768) ============
__global__ void k_greduce(const float* __restrict__ qkv_g,
                          const float* __restrict__ part,
                          float* __restrict__ og_mean) {
  __shared__ float red[4][64];
  int bh = blockIdx.x;
  int b = bh / 12, h = bh - b * 12;
  int tid = threadIdx.x;
  int qi = tid >> 6, d = tid & 63;
  float M = -1e30f, L = 0.f, A = 0.f;
  float qd = qkv_g[qi * 2304 + h * 64 + d];
#pragma unroll
  for (int gk = 0; gk < 4; ++gk) {
    float kd = qkv_g[gk * 2304 + 768 + h * 64 + d];
    float prod = qd * kd;
#pragma unroll
    for (int o = 1; o < 64; o <<= 1) prod += __shfl_xor(prod, o);
    float s = prod * SCALE;
    float Mn = fmaxf(M, s);
    float f = expf(M - Mn), e = expf(s - Mn);
    float vd = qkv_g[gk * 2304 + 1536 + h * 64 + d];
    A = A * f + e * vd;
    L = L * f + e;
    M = Mn;
  }
  for (int p = 0; p < 64; ++p) {
    int pbase = ((b * 12 + h) * 64 + p) * 272;
    float mp = part[pbase + 256 + qi];
    float lp = part[pbase + 260 + qi];
    float ap = part[pbase + qi * 64 + d];
    float Mn = fmaxf(M, mp);
    float f = expf(M - Mn), e = expf(mp - Mn);
    A = A * f + ap * e;
    L = L * f + lp * e;
    M = Mn;
  }
  red[qi][d] = A / L;
  __syncthreads();
  if (tid < 64) {
    float s = (red[0][d] + red[1][d] + red[2][d] + red[3][d]) * 0.25f;
    og_mean[b * 768 + h * 64 + d] = s;
  }
}

// ============ G4: g_term = og_mean @ w_out (B x 768), fp32 ============
__global__ void k_gterm(const float* __restrict__ og_mean,
                        const float* __restrict__ w_out,
                        float* __restrict__ g_term) {
  int idx = blockIdx.x * 256 + threadIdx.x;   // 0..6143
  int b = idx / 768, c = idx - b * 768;
  const float* op = og_mean + b * 768;
  float s = 0.f;
  for (int d = 0; d < 768; ++d) s += op[d] * w_out[d * 768 + c];
  g_term[idx] = s;
}

extern "C" void kernel_launch(void* const* d_in, const int* in_sizes, int n_in,
                              void* d_out, int out_size, void* d_ws, size_t ws_size,
                              hipStream_t stream) {
  const float* x      = (const float*)d_in[0];
  const float* w_qkv  = (const float*)d_in[1];
  const float* w_out  = (const float*)d_in[2];
  const float* qnw    = (const float*)d_in[3];
  const float* knw    = (const float*)d_in[4];
  const float* gtok   = (const float*)d_in[5];
  float* out = (float*)d_out;

  // ---- ws layout (~117 MB) ----
  ushort* WhiQ = (ushort*)d_ws;                 // 2304*768
  ushort* WloQ = WhiQ + 2304 * 768;
  ushort* WhiO = WloQ + 2304 * 768;             // 768*768
  ushort* WloO = WhiO + 768 * 768;
  ushort* o_hi = WloO + 768 * 768;              // 32768*768
  ushort* o_lo = o_hi + 32768 * 768;
  float* qkv_g   = (float*)(o_lo + 32768 * 768);
  float* part    = qkv_g + 9216;                // 8*12*64*272
  float* og_mean = part + 8 * 12 * 64 * 272;
  float* g_term  = og_mean + 6144;

  // x hi/lo planes live in d_out until the final projection overwrites it
  ushort* xh = (ushort*)d_out;                  // 32768*768
  ushort* xl = xh + 32768 * 768;

  k_prep  <<<dim3(36, 12), 256, 0, stream>>>(w_qkv, 2304, 0, WhiQ, WloQ);
  k_prep  <<<dim3(12, 12), 256, 0, stream>>>(w_out,  768, 1, WhiO, WloO);
  k_gqkv  <<<36,    256, 0, stream>>>(gtok, w_qkv, qkv_g);
  k_xsplit<<<12288, 256, 0, stream>>>(x, xh, xl);

  k_fused <<<1536, 512, 0, stream>>>(xh, xl, WhiQ, WloQ, qnw, knw, qkv_g, part, o_hi, o_lo);

  k_greduce<<<96, 256, 0, stream>>>(qkv_g, part, og_mean);
  k_gterm  <<<24, 256, 0, stream>>>(og_mean, w_out, g_term);
  k_proj8 <<<512, 512, 0, stream>>>(o_hi, o_lo, WhiO, WloO, g_term, out);
}